// Round 2
// baseline (516.889 us; speedup 1.0000x reference)
//
#include <hip/hip_runtime.h>
#include <math.h>

#define DIM 1024
#define DEPTH 7
#define PAR 8
#define N_NODES 255   // 2^(DEPTH+1) - 1
#define WIDTH 2040    // PAR * N_NODES
// f16-dot error sigma ~3e-4; 0.01 is ~30 sigma.
#define MARGIN 0.01f

// lane that holds tree p's reduced logit after the fold network (bits 8/16/32)
#define REPLANE(p) ((((p) & 1) << 3) | ((((p) >> 1) & 1) << 4) | ((((p) >> 2) & 1) << 5))

typedef _Float16 half2v __attribute__((ext_vector_type(2)));

__device__ __forceinline__ half2v as_h2(unsigned int u) {
    union { unsigned int u; half2v h; } c; c.u = u; return c.h;
}
__device__ __forceinline__ unsigned int pack_h2(float a, float b) {
    union { half2v h; unsigned int u; } c;
    c.h = (half2v){(_Float16)a, (_Float16)b};   // v_cvt_f16_f32 is RTNE
    return c.u;
}

// f16 dot2 with fp32 accumulate; builtin if available, exact fallback otherwise
__device__ __forceinline__ float dot2h(unsigned int a, unsigned int b, float c) {
#if __has_builtin(__builtin_amdgcn_fdot2)
    return __builtin_amdgcn_fdot2(as_h2(a), as_h2(b), c, false);
#else
    half2v ha = as_h2(a), hb = as_h2(b);
    c = fmaf((float)ha.x, (float)hb.x, c);
    return fmaf((float)ha.y, (float)hb.y, c);
#endif
}

// fold two per-lane partial sums into one register, separating them by lane bit K.
__device__ __forceinline__ float foldK(float a, float b, int K) {
    const bool hi = (threadIdx.x & (unsigned)K) != 0;
    const float keep = hi ? b : a;
    const float send = hi ? a : b;
    return keep + __shfl_xor(send, K, 64);
}

// ---------------------------------------------------------------------------
// Fused prep: blocks [0,512) transpose+convert W_out f32 [DIM][WIDTH] ->
// WoT f16 [WIDTH][DIM]; blocks [512,...) convert W_in f32 -> f16 packed.
// ---------------------------------------------------------------------------
#define TRANS_BLOCKS 512   // 32 (WIDTH/64 tiles) x 16 (DIM/64 tiles)

__global__ __launch_bounds__(256) void prep_kernel(
    const float* __restrict__ W_out,      // [DIM][WIDTH] f32
    const float* __restrict__ W_in,       // [WIDTH][DIM] f32
    unsigned short* __restrict__ WoT,     // [WIDTH][DIM] f16
    unsigned int* __restrict__ Wh)        // [WIDTH][DIM/2] f16-pair dwords
{
    __shared__ float tile[64][65];
    if (blockIdx.x < TRANS_BLOCKS) {
        const int w0 = (int)(blockIdx.x & 31) * 64;
        const int d0 = (int)(blockIdx.x >> 5) * 64;
        const int tid = (int)threadIdx.x;
        const int sub = tid & 15;
        const int grp = tid >> 4;

        #pragma unroll
        for (int pass = 0; pass < 4; ++pass) {
            const int dl = pass * 16 + grp;
            const int wl = sub * 4;
            const int w = w0 + wl;
            const int d = d0 + dl;
            float4 v = make_float4(0.f, 0.f, 0.f, 0.f);
            if (w + 3 < WIDTH) {
                v = *(const float4*)(W_out + (size_t)d * WIDTH + w);
            } else {
                float t0 = (w + 0 < WIDTH) ? W_out[(size_t)d * WIDTH + w + 0] : 0.f;
                float t1 = (w + 1 < WIDTH) ? W_out[(size_t)d * WIDTH + w + 1] : 0.f;
                float t2 = (w + 2 < WIDTH) ? W_out[(size_t)d * WIDTH + w + 2] : 0.f;
                float t3 = (w + 3 < WIDTH) ? W_out[(size_t)d * WIDTH + w + 3] : 0.f;
                v = make_float4(t0, t1, t2, t3);
            }
            tile[dl][wl + 0] = v.x; tile[dl][wl + 1] = v.y;
            tile[dl][wl + 2] = v.z; tile[dl][wl + 3] = v.w;
        }
        __syncthreads();
        #pragma unroll
        for (int pass = 0; pass < 4; ++pass) {
            const int wl = pass * 16 + grp;
            const int dl = sub * 4;
            const int w = w0 + wl;
            if (w < WIDTH) {
                uint2 pk;
                pk.x = pack_h2(tile[dl + 0][wl], tile[dl + 1][wl]);
                pk.y = pack_h2(tile[dl + 2][wl], tile[dl + 3][wl]);
                *(uint2*)(WoT + (size_t)w * DIM + d0 + dl) = pk;
            }
        }
    } else {
        const int n4 = WIDTH * DIM / 4;
        const int nthr = ((int)gridDim.x - TRANS_BLOCKS) * 256;
        for (int i = ((int)blockIdx.x - TRANS_BLOCKS) * 256 + (int)threadIdx.x;
             i < n4; i += nthr) {
            float4 v = ((const float4*)W_in)[i];
            uint2 pk;
            pk.x = pack_h2(v.x, v.y);
            pk.y = pack_h2(v.z, v.w);
            ((uint2*)Wh)[i] = pk;
        }
    }
}

// ---------------------------------------------------------------------------
// Main kernel: one wave per row. __launch_bounds__(256, 8) caps VGPR at 64 ->
// 8 waves/SIMD (32/CU). The level body is minimal-live-state per-tree
// load->compute interleave; latency hiding comes from TLP, not batched ILP.
// ---------------------------------------------------------------------------
__global__ __launch_bounds__(256, 8) void fff_f16_kernel(
    const float* __restrict__ x,            // [B, DIM] f32
    const float* __restrict__ W_in,         // [WIDTH, DIM] f32 (repair only)
    const float* __restrict__ b_in,         // [WIDTH] f32
    const unsigned int* __restrict__ Wh,    // f16 W_in  [WIDTH][DIM/2] dwords
    const unsigned short* __restrict__ WoT, // f16 W_out^T [WIDTH][DIM]
    float* __restrict__ out,                // [B, DIM] f32
    int B)
{
    const int wave = (int)((blockIdx.x * blockDim.x + threadIdx.x) >> 6);
    const int lane = (int)(threadIdx.x & 63);
    if (wave >= B) return;

    const float* xr = x + (size_t)wave * DIM;
    unsigned int xp[8];
    {
        float4 a0 = *(const float4*)(xr + lane * 8 + 0);
        float4 a1 = *(const float4*)(xr + lane * 8 + 4);
        float4 a2 = *(const float4*)(xr + 512 + lane * 8 + 0);
        float4 a3 = *(const float4*)(xr + 512 + lane * 8 + 4);
        xp[0] = pack_h2(a0.x, a0.y);
        xp[1] = pack_h2(a0.z, a0.w);
        xp[2] = pack_h2(a1.x, a1.y);
        xp[3] = pack_h2(a1.z, a1.w);
        xp[4] = pack_h2(a2.x, a2.y);
        xp[5] = pack_h2(a2.z, a2.w);
        xp[6] = pack_h2(a3.x, a3.y);
        xp[7] = pack_h2(a3.z, a3.w);
    }

    float acc[16];
    #pragma unroll
    for (int i = 0; i < 16; ++i) acc[i] = 0.f;

    unsigned long long nodes = 0ULL;   // 8 x u8 node indices (all < 255)
    const int myp = ((lane >> 3) & 1) | (((lane >> 4) & 1) << 1) | (((lane >> 5) & 1) << 2);

    #pragma unroll 1
    for (int d = 0; d <= DEPTH; ++d) {
        int gidx[PAR];
        #pragma unroll
        for (int p = 0; p < PAR; ++p) {
            const int np = (int)((nodes >> (8 * p)) & 0xffULL);
            gidx[p] = p * N_NODES + np;
        }

        // Phase A: per-tree load + dot (small live set; TLP hides latency)
        float partial[PAR];
        #pragma unroll
        for (int p = 0; p < PAR; ++p) {
            const unsigned int* wr = Wh + (size_t)gidx[p] * (DIM / 2);
            const uint4 u0 = *(const uint4*)(wr + lane * 4);
            const uint4 u1 = *(const uint4*)(wr + 256 + lane * 4);
            float s = 0.f;
            s = dot2h(xp[0], u0.x, s);
            s = dot2h(xp[1], u0.y, s);
            s = dot2h(xp[2], u0.z, s);
            s = dot2h(xp[3], u0.w, s);
            s = dot2h(xp[4], u1.x, s);
            s = dot2h(xp[5], u1.y, s);
            s = dot2h(xp[6], u1.z, s);
            s = dot2h(xp[7], u1.w, s);
            partial[p] = s;
        }

        // Phase B: fold network over lane bits {8,16,32}, butterfly over {1,2,4}
        const float c01 = foldK(partial[0], partial[1], 8);
        const float c23 = foldK(partial[2], partial[3], 8);
        const float c45 = foldK(partial[4], partial[5], 8);
        const float c67 = foldK(partial[6], partial[7], 8);
        const float d0f = foldK(c01, c23, 16);
        const float d1f = foldK(c45, c67, 16);
        float e = foldK(d0f, d1f, 32);
        e += __shfl_xor(e, 1, 64);
        e += __shfl_xor(e, 2, 64);
        e += __shfl_xor(e, 4, 64);

        const int ga = (lane & 8) ? gidx[1] : gidx[0];
        const int gb = (lane & 8) ? gidx[3] : gidx[2];
        const int gc = (lane & 8) ? gidx[5] : gidx[4];
        const int gd = (lane & 8) ? gidx[7] : gidx[6];
        const int ge = (lane & 16) ? gb : ga;
        const int gf = (lane & 16) ? gd : gc;
        const int gmine = (lane & 32) ? gf : ge;
        float my = e + b_in[gmine];

        // Repair: near-zero logits recomputed in fp32 (decisions must match numpy)
        if (d < DEPTH) {
            const unsigned long long bal = __ballot(fabsf(my) < MARGIN);
            unsigned rm = 0;
            #pragma unroll
            for (int p = 0; p < PAR; ++p)
                rm |= ((unsigned)((bal >> REPLANE(p)) & 1ULL)) << p;
            if (rm) {
                const float4 fa = *(const float4*)(xr + lane * 8 + 0);
                const float4 fb = *(const float4*)(xr + lane * 8 + 4);
                const float4 fc = *(const float4*)(xr + 512 + lane * 8 + 0);
                const float4 fd = *(const float4*)(xr + 512 + lane * 8 + 4);
                while (rm) {
                    const int p = __builtin_ctz(rm); rm &= (rm - 1u);
                    const int gi = gidx[p];
                    const float* wr = W_in + (size_t)gi * DIM;
                    const float4 wa = *(const float4*)(wr + lane * 8 + 0);
                    const float4 wb = *(const float4*)(wr + lane * 8 + 4);
                    const float4 wc = *(const float4*)(wr + 512 + lane * 8 + 0);
                    const float4 wd = *(const float4*)(wr + 512 + lane * 8 + 4);
                    float s = 0.f;
                    s = fmaf(fa.x, wa.x, s); s = fmaf(fa.y, wa.y, s);
                    s = fmaf(fa.z, wa.z, s); s = fmaf(fa.w, wa.w, s);
                    s = fmaf(fb.x, wb.x, s); s = fmaf(fb.y, wb.y, s);
                    s = fmaf(fb.z, wb.z, s); s = fmaf(fb.w, wb.w, s);
                    s = fmaf(fc.x, wc.x, s); s = fmaf(fc.y, wc.y, s);
                    s = fmaf(fc.z, wc.z, s); s = fmaf(fc.w, wc.w, s);
                    s = fmaf(fd.x, wd.x, s); s = fmaf(fd.y, wd.y, s);
                    s = fmaf(fd.z, wd.z, s); s = fmaf(fd.w, wd.w, s);
                    #pragma unroll
                    for (int off = 32; off >= 1; off >>= 1)
                        s += __shfl_xor(s, off, 64);
                    const float lf = s + b_in[gi];
                    my = (myp == p) ? lf : my;
                }
            }
        }

        // per-lane silu (8 trees in parallel), decisions via one ballot
        const float act_mine = my / (1.0f + __expf(-my));
        const unsigned long long pos = __ballot(my > 0.0f);

        float act[PAR];
        #pragma unroll
        for (int p = 0; p < PAR; ++p)
            act[p] = __shfl(act_mine, REPLANE(p), 64);

        // Phase C: per-tree load + f16 axpy into fp32 acc (v_fma_mix pattern)
        #pragma unroll
        for (int p = 0; p < PAR; ++p) {
            const unsigned short* wo = WoT + (size_t)gidx[p] * DIM;
            const uint4 u0 = *(const uint4*)(wo + lane * 8);
            const uint4 u1 = *(const uint4*)(wo + 512 + lane * 8);
            const float a_ = act[p];
            half2v h_;
            h_ = as_h2(u0.x); acc[0]  = fmaf((float)h_.x, a_, acc[0]);  acc[1]  = fmaf((float)h_.y, a_, acc[1]);
            h_ = as_h2(u0.y); acc[2]  = fmaf((float)h_.x, a_, acc[2]);  acc[3]  = fmaf((float)h_.y, a_, acc[3]);
            h_ = as_h2(u0.z); acc[4]  = fmaf((float)h_.x, a_, acc[4]);  acc[5]  = fmaf((float)h_.y, a_, acc[5]);
            h_ = as_h2(u0.w); acc[6]  = fmaf((float)h_.x, a_, acc[6]);  acc[7]  = fmaf((float)h_.y, a_, acc[7]);
            h_ = as_h2(u1.x); acc[8]  = fmaf((float)h_.x, a_, acc[8]);  acc[9]  = fmaf((float)h_.y, a_, acc[9]);
            h_ = as_h2(u1.y); acc[10] = fmaf((float)h_.x, a_, acc[10]); acc[11] = fmaf((float)h_.y, a_, acc[11]);
            h_ = as_h2(u1.z); acc[12] = fmaf((float)h_.x, a_, acc[12]); acc[13] = fmaf((float)h_.y, a_, acc[13]);
            h_ = as_h2(u1.w); acc[14] = fmaf((float)h_.x, a_, acc[14]); acc[15] = fmaf((float)h_.y, a_, acc[15]);

            if (d < DEPTH) {
                const int np = (int)((nodes >> (8 * p)) & 0xffULL);
                const unsigned long long nn = (unsigned long long)
                    (2 * np + 1 + (int)((pos >> REPLANE(p)) & 1ULL));
                nodes = (nodes & ~(0xffULL << (8 * p))) | (nn << (8 * p));
            }
        }
    }

    float* orow = out + (size_t)wave * DIM;
    *(float4*)(orow + lane * 8 + 0)       = make_float4(acc[0],  acc[1],  acc[2],  acc[3]);
    *(float4*)(orow + lane * 8 + 4)       = make_float4(acc[4],  acc[5],  acc[6],  acc[7]);
    *(float4*)(orow + 512 + lane * 8 + 0) = make_float4(acc[8],  acc[9],  acc[10], acc[11]);
    *(float4*)(orow + 512 + lane * 8 + 4) = make_float4(acc[12], acc[13], acc[14], acc[15]);
}

// ---------------------------------------------------------------------------
// Fallback (no workspace): fp32 gather both stages. Correct but slow.
// ---------------------------------------------------------------------------
__global__ __launch_bounds__(256) void fff_fallback_kernel(
    const float* __restrict__ x, const float* __restrict__ W_in,
    const float* __restrict__ b_in, const float* __restrict__ W_out,
    float* __restrict__ out, int B)
{
    const int wave = (int)((blockIdx.x * blockDim.x + threadIdx.x) >> 6);
    const int lane = (int)(threadIdx.x & 63);
    if (wave >= B) return;

    const float* xr = x + (size_t)wave * DIM;
    float4 x4[4];
    x4[0] = *(const float4*)(xr + lane * 8 + 0);
    x4[1] = *(const float4*)(xr + lane * 8 + 4);
    x4[2] = *(const float4*)(xr + 512 + lane * 8 + 0);
    x4[3] = *(const float4*)(xr + 512 + lane * 8 + 4);

    float acc[16];
    #pragma unroll
    for (int i = 0; i < 16; ++i) acc[i] = 0.f;
    int node[PAR];
    #pragma unroll
    for (int p = 0; p < PAR; ++p) node[p] = 0;

    for (int d = 0; d <= DEPTH; ++d) {
        #pragma unroll
        for (int p = 0; p < PAR; ++p) {
            const int gidx = p * N_NODES + node[p];
            const float* wr = W_in + (size_t)gidx * DIM;
            const float4 wa = *(const float4*)(wr + lane * 8 + 0);
            const float4 wb = *(const float4*)(wr + lane * 8 + 4);
            const float4 wc = *(const float4*)(wr + 512 + lane * 8 + 0);
            const float4 wd = *(const float4*)(wr + 512 + lane * 8 + 4);
            float s = 0.f;
            s = fmaf(x4[0].x, wa.x, s); s = fmaf(x4[0].y, wa.y, s);
            s = fmaf(x4[0].z, wa.z, s); s = fmaf(x4[0].w, wa.w, s);
            s = fmaf(x4[1].x, wb.x, s); s = fmaf(x4[1].y, wb.y, s);
            s = fmaf(x4[1].z, wb.z, s); s = fmaf(x4[1].w, wb.w, s);
            s = fmaf(x4[2].x, wc.x, s); s = fmaf(x4[2].y, wc.y, s);
            s = fmaf(x4[2].z, wc.z, s); s = fmaf(x4[2].w, wc.w, s);
            s = fmaf(x4[3].x, wd.x, s); s = fmaf(x4[3].y, wd.y, s);
            s = fmaf(x4[3].z, wd.z, s); s = fmaf(x4[3].w, wd.w, s);
            #pragma unroll
            for (int off = 32; off >= 1; off >>= 1)
                s += __shfl_xor(s, off, 64);
            const float logit = s + b_in[gidx];
            const float act = logit / (1.0f + __expf(-logit));
            #pragma unroll
            for (int k = 0; k < 2; ++k) {
                #pragma unroll
                for (int j = 0; j < 8; ++j) {
                    const int e = k * 512 + lane * 8 + j;
                    acc[k * 8 + j] = fmaf(act, W_out[(size_t)e * WIDTH + gidx], acc[k * 8 + j]);
                }
            }
            node[p] = 2 * node[p] + 1 + ((logit > 0.0f) ? 1 : 0);
        }
    }

    float* orow = out + (size_t)wave * DIM;
    *(float4*)(orow + lane * 8 + 0)       = make_float4(acc[0],  acc[1],  acc[2],  acc[3]);
    *(float4*)(orow + lane * 8 + 4)       = make_float4(acc[4],  acc[5],  acc[6],  acc[7]);
    *(float4*)(orow + 512 + lane * 8 + 0) = make_float4(acc[8],  acc[9],  acc[10], acc[11]);
    *(float4*)(orow + 512 + lane * 8 + 4) = make_float4(acc[12], acc[13], acc[14], acc[15]);
}

extern "C" void kernel_launch(void* const* d_in, const int* in_sizes, int n_in,
                              void* d_out, int out_size, void* d_ws, size_t ws_size,
                              hipStream_t stream) {
    const float* oldx  = (const float*)d_in[0];
    const float* W_in  = (const float*)d_in[1];
    const float* b_in  = (const float*)d_in[2];
    const float* W_out = (const float*)d_in[3];
    float* out = (float*)d_out;

    const int B = in_sizes[0] / DIM;   // 8192 rows

    const size_t half = (size_t)WIDTH * DIM * sizeof(unsigned short);  // 4.18 MB
    const bool use_lp = (ws_size >= 2 * half) && (d_ws != nullptr);

    const int blocks = (B + 3) / 4;    // 4 waves (256 threads) per block

    if (use_lp) {
        unsigned short* WoT = (unsigned short*)d_ws;
        unsigned int*   Wh  = (unsigned int*)((char*)d_ws + half);
        prep_kernel<<<TRANS_BLOCKS + 1024, 256, 0, stream>>>(W_out, W_in, WoT, Wh);
        fff_f16_kernel<<<blocks, 256, 0, stream>>>(oldx, W_in, b_in, Wh, WoT, out, B);
    } else {
        fff_fallback_kernel<<<blocks, 256, 0, stream>>>(oldx, W_in, b_in, W_out, out, B);
    }
}

// Round 3
// 203.858 us; speedup vs baseline: 2.5355x; 2.5355x over previous
//
#include <hip/hip_runtime.h>
#include <math.h>

#define DIM 1024
#define DEPTH 7
#define PAR 8
#define N_NODES 255   // 2^(DEPTH+1) - 1
#define WIDTH 2040    // PAR * N_NODES
// f16-dot error sigma ~3e-4; 0.01 is ~30 sigma.
#define MARGIN 0.01f

// lane that holds tree p's reduced logit after the fold network (bits 8/16/32)
#define REPLANE(p) ((((p) & 1) << 3) | ((((p) >> 1) & 1) << 4) | ((((p) >> 2) & 1) << 5))

// pin a uint4's components in VGPRs at this program point: forces the load to
// have completed here and prevents the allocator sinking/splitting the batch.
#define PIN4(u) asm volatile("" : "+v"((u).x), "+v"((u).y), "+v"((u).z), "+v"((u).w))

typedef _Float16 half2v __attribute__((ext_vector_type(2)));

__device__ __forceinline__ half2v as_h2(unsigned int u) {
    union { unsigned int u; half2v h; } c; c.u = u; return c.h;
}
__device__ __forceinline__ unsigned int pack_h2(float a, float b) {
    union { half2v h; unsigned int u; } c;
    c.h = (half2v){(_Float16)a, (_Float16)b};   // v_cvt_f16_f32 is RTNE
    return c.u;
}

// f16 dot2 with fp32 accumulate; builtin if available, exact fallback otherwise
__device__ __forceinline__ float dot2h(unsigned int a, unsigned int b, float c) {
#if __has_builtin(__builtin_amdgcn_fdot2)
    return __builtin_amdgcn_fdot2(as_h2(a), as_h2(b), c, false);
#else
    half2v ha = as_h2(a), hb = as_h2(b);
    c = fmaf((float)ha.x, (float)hb.x, c);
    return fmaf((float)ha.y, (float)hb.y, c);
#endif
}

// fold two per-lane partial sums into one register, separating them by lane bit K.
__device__ __forceinline__ float foldK(float a, float b, int K) {
    const bool hi = (threadIdx.x & (unsigned)K) != 0;
    const float keep = hi ? b : a;
    const float send = hi ? a : b;
    return keep + __shfl_xor(send, K, 64);
}

// ---------------------------------------------------------------------------
// Fused prep: blocks [0,512) transpose+convert W_out f32 [DIM][WIDTH] ->
// WoT f16 [WIDTH][DIM]; blocks [512,...) convert W_in f32 -> f16 packed.
// ---------------------------------------------------------------------------
#define TRANS_BLOCKS 512   // 32 (WIDTH/64 tiles) x 16 (DIM/64 tiles)

__global__ __launch_bounds__(256) void prep_kernel(
    const float* __restrict__ W_out,      // [DIM][WIDTH] f32
    const float* __restrict__ W_in,       // [WIDTH][DIM] f32
    unsigned short* __restrict__ WoT,     // [WIDTH][DIM] f16
    unsigned int* __restrict__ Wh)        // [WIDTH][DIM/2] f16-pair dwords
{
    __shared__ float tile[64][65];
    if (blockIdx.x < TRANS_BLOCKS) {
        const int w0 = (int)(blockIdx.x & 31) * 64;
        const int d0 = (int)(blockIdx.x >> 5) * 64;
        const int tid = (int)threadIdx.x;
        const int sub = tid & 15;
        const int grp = tid >> 4;

        #pragma unroll
        for (int pass = 0; pass < 4; ++pass) {
            const int dl = pass * 16 + grp;
            const int wl = sub * 4;
            const int w = w0 + wl;
            const int d = d0 + dl;
            float4 v = make_float4(0.f, 0.f, 0.f, 0.f);
            if (w + 3 < WIDTH) {
                v = *(const float4*)(W_out + (size_t)d * WIDTH + w);
            } else {
                float t0 = (w + 0 < WIDTH) ? W_out[(size_t)d * WIDTH + w + 0] : 0.f;
                float t1 = (w + 1 < WIDTH) ? W_out[(size_t)d * WIDTH + w + 1] : 0.f;
                float t2 = (w + 2 < WIDTH) ? W_out[(size_t)d * WIDTH + w + 2] : 0.f;
                float t3 = (w + 3 < WIDTH) ? W_out[(size_t)d * WIDTH + w + 3] : 0.f;
                v = make_float4(t0, t1, t2, t3);
            }
            tile[dl][wl + 0] = v.x; tile[dl][wl + 1] = v.y;
            tile[dl][wl + 2] = v.z; tile[dl][wl + 3] = v.w;
        }
        __syncthreads();
        #pragma unroll
        for (int pass = 0; pass < 4; ++pass) {
            const int wl = pass * 16 + grp;
            const int dl = sub * 4;
            const int w = w0 + wl;
            if (w < WIDTH) {
                uint2 pk;
                pk.x = pack_h2(tile[dl + 0][wl], tile[dl + 1][wl]);
                pk.y = pack_h2(tile[dl + 2][wl], tile[dl + 3][wl]);
                *(uint2*)(WoT + (size_t)w * DIM + d0 + dl) = pk;
            }
        }
    } else {
        const int n4 = WIDTH * DIM / 4;
        const int nthr = ((int)gridDim.x - TRANS_BLOCKS) * 256;
        for (int i = ((int)blockIdx.x - TRANS_BLOCKS) * 256 + (int)threadIdx.x;
             i < n4; i += nthr) {
            float4 v = ((const float4*)W_in)[i];
            uint2 pk;
            pk.x = pack_h2(v.x, v.y);
            pk.y = pack_h2(v.z, v.w);
            ((uint2*)Wh)[i] = pk;
        }
    }
}

// ---------------------------------------------------------------------------
// Main kernel: one wave per row. 4-waves/SIMD tier (VGPR <= 128); within the
// tier the free registers are spent on pinned load batches:
//   A: 16 loads -> pin -> 64 dots      (1 memory wait per level, not 8)
//   C: 16 loads issued right after the dots; latency hides under the
//      fold network + repair + silu; pinned just before the FMA chain.
// ---------------------------------------------------------------------------
__global__ __launch_bounds__(256, 4) void fff_f16_kernel(
    const float* __restrict__ x,            // [B, DIM] f32
    const float* __restrict__ W_in,         // [WIDTH, DIM] f32 (repair only)
    const float* __restrict__ b_in,         // [WIDTH] f32
    const unsigned int* __restrict__ Wh,    // f16 W_in  [WIDTH][DIM/2] dwords
    const unsigned short* __restrict__ WoT, // f16 W_out^T [WIDTH][DIM]
    float* __restrict__ out,                // [B, DIM] f32
    int B)
{
    const int wave = (int)((blockIdx.x * blockDim.x + threadIdx.x) >> 6);
    const int lane = (int)(threadIdx.x & 63);
    if (wave >= B) return;

    const float* xr = x + (size_t)wave * DIM;
    unsigned int xp[8];
    {
        float4 a0 = *(const float4*)(xr + lane * 8 + 0);
        float4 a1 = *(const float4*)(xr + lane * 8 + 4);
        float4 a2 = *(const float4*)(xr + 512 + lane * 8 + 0);
        float4 a3 = *(const float4*)(xr + 512 + lane * 8 + 4);
        xp[0] = pack_h2(a0.x, a0.y);
        xp[1] = pack_h2(a0.z, a0.w);
        xp[2] = pack_h2(a1.x, a1.y);
        xp[3] = pack_h2(a1.z, a1.w);
        xp[4] = pack_h2(a2.x, a2.y);
        xp[5] = pack_h2(a2.z, a2.w);
        xp[6] = pack_h2(a3.x, a3.y);
        xp[7] = pack_h2(a3.z, a3.w);
    }

    float acc[16];
    #pragma unroll
    for (int i = 0; i < 16; ++i) acc[i] = 0.f;

    unsigned long long nodes = 0ULL;   // 8 x u8 node indices (all < 255)
    const int myp = ((lane >> 3) & 1) | (((lane >> 4) & 1) << 1) | (((lane >> 5) & 1) << 2);

    #pragma unroll 1
    for (int d = 0; d <= DEPTH; ++d) {
        int gidx[PAR];
        #pragma unroll
        for (int p = 0; p < PAR; ++p) {
            const int np = (int)((nodes >> (8 * p)) & 0xffULL);
            gidx[p] = p * N_NODES + np;
        }

        // Phase A: issue all 16 Wh loads, pin, then consume with 64 dot2s.
        uint4 ua[PAR], ub[PAR];
        #pragma unroll
        for (int p = 0; p < PAR; ++p) {
            const unsigned int* wr = Wh + (size_t)gidx[p] * (DIM / 2);
            ua[p] = *(const uint4*)(wr + lane * 4);
            ub[p] = *(const uint4*)(wr + 256 + lane * 4);
        }
        #pragma unroll
        for (int p = 0; p < PAR; ++p) { PIN4(ua[p]); PIN4(ub[p]); }

        float partial[PAR];
        #pragma unroll
        for (int p = 0; p < PAR; ++p) {
            float s = 0.f;
            s = dot2h(xp[0], ua[p].x, s);
            s = dot2h(xp[1], ua[p].y, s);
            s = dot2h(xp[2], ua[p].z, s);
            s = dot2h(xp[3], ua[p].w, s);
            s = dot2h(xp[4], ub[p].x, s);
            s = dot2h(xp[5], ub[p].y, s);
            s = dot2h(xp[6], ub[p].z, s);
            s = dot2h(xp[7], ub[p].w, s);
            partial[p] = s;
        }

        // Phase C loads issued NOW: addresses depend only on gidx. Their
        // latency hides under the fold network + repair + silu below.
        uint4 wv0[PAR], wv1[PAR];
        #pragma unroll
        for (int p = 0; p < PAR; ++p) {
            const unsigned short* wo = WoT + (size_t)gidx[p] * DIM;
            wv0[p] = *(const uint4*)(wo + lane * 8);
            wv1[p] = *(const uint4*)(wo + 512 + lane * 8);
        }

        // Phase B: fold network over lane bits {8,16,32}, butterfly over {1,2,4}
        const float c01 = foldK(partial[0], partial[1], 8);
        const float c23 = foldK(partial[2], partial[3], 8);
        const float c45 = foldK(partial[4], partial[5], 8);
        const float c67 = foldK(partial[6], partial[7], 8);
        const float d0f = foldK(c01, c23, 16);
        const float d1f = foldK(c45, c67, 16);
        float e = foldK(d0f, d1f, 32);
        e += __shfl_xor(e, 1, 64);
        e += __shfl_xor(e, 2, 64);
        e += __shfl_xor(e, 4, 64);

        const int ga = (lane & 8) ? gidx[1] : gidx[0];
        const int gb = (lane & 8) ? gidx[3] : gidx[2];
        const int gc = (lane & 8) ? gidx[5] : gidx[4];
        const int gd = (lane & 8) ? gidx[7] : gidx[6];
        const int ge = (lane & 16) ? gb : ga;
        const int gf = (lane & 16) ? gd : gc;
        const int gmine = (lane & 32) ? gf : ge;
        float my = e + b_in[gmine];

        // Repair: near-zero logits recomputed in fp32 (decisions must match
        // numpy). Pairwise float4 processing keeps transient pressure low --
        // this cold branch must not raise the kernel's peak VGPR count.
        if (d < DEPTH) {
            const unsigned long long bal = __ballot(fabsf(my) < MARGIN);
            unsigned rm = 0;
            #pragma unroll
            for (int p = 0; p < PAR; ++p)
                rm |= ((unsigned)((bal >> REPLANE(p)) & 1ULL)) << p;
            if (rm) {
                while (rm) {
                    const int p = __builtin_ctz(rm); rm &= (rm - 1u);
                    const int gi = gidx[p];
                    const float* wr = W_in + (size_t)gi * DIM;
                    float s = 0.f;
                    #pragma unroll
                    for (int q = 0; q < 4; ++q) {
                        const int off = (q & 1) * 4 + (q >> 1) * 512 + lane * 8;
                        const float4 fx = *(const float4*)(xr + off);
                        const float4 fw = *(const float4*)(wr + off);
                        s = fmaf(fx.x, fw.x, s); s = fmaf(fx.y, fw.y, s);
                        s = fmaf(fx.z, fw.z, s); s = fmaf(fx.w, fw.w, s);
                    }
                    #pragma unroll
                    for (int off = 32; off >= 1; off >>= 1)
                        s += __shfl_xor(s, off, 64);
                    const float lf = s + b_in[gi];
                    my = (myp == p) ? lf : my;
                }
            }
        }

        // per-lane silu (8 trees in parallel), decisions via one ballot
        const float act_mine = my / (1.0f + __expf(-my));
        const unsigned long long pos = __ballot(my > 0.0f);

        float act[PAR];
        #pragma unroll
        for (int p = 0; p < PAR; ++p)
            act[p] = __shfl(act_mine, REPLANE(p), 64);

        // Pin the C batch: all 16 loads must be complete here; FMA chain
        // below runs waitless.
        #pragma unroll
        for (int p = 0; p < PAR; ++p) { PIN4(wv0[p]); PIN4(wv1[p]); }

        // Phase C: f16 axpy into fp32 acc (v_fma_mix pattern)
        #pragma unroll
        for (int p = 0; p < PAR; ++p) {
            const float a_ = act[p];
            half2v h_;
            h_ = as_h2(wv0[p].x); acc[0]  = fmaf((float)h_.x, a_, acc[0]);  acc[1]  = fmaf((float)h_.y, a_, acc[1]);
            h_ = as_h2(wv0[p].y); acc[2]  = fmaf((float)h_.x, a_, acc[2]);  acc[3]  = fmaf((float)h_.y, a_, acc[3]);
            h_ = as_h2(wv0[p].z); acc[4]  = fmaf((float)h_.x, a_, acc[4]);  acc[5]  = fmaf((float)h_.y, a_, acc[5]);
            h_ = as_h2(wv0[p].w); acc[6]  = fmaf((float)h_.x, a_, acc[6]);  acc[7]  = fmaf((float)h_.y, a_, acc[7]);
            h_ = as_h2(wv1[p].x); acc[8]  = fmaf((float)h_.x, a_, acc[8]);  acc[9]  = fmaf((float)h_.y, a_, acc[9]);
            h_ = as_h2(wv1[p].y); acc[10] = fmaf((float)h_.x, a_, acc[10]); acc[11] = fmaf((float)h_.y, a_, acc[11]);
            h_ = as_h2(wv1[p].z); acc[12] = fmaf((float)h_.x, a_, acc[12]); acc[13] = fmaf((float)h_.y, a_, acc[13]);
            h_ = as_h2(wv1[p].w); acc[14] = fmaf((float)h_.x, a_, acc[14]); acc[15] = fmaf((float)h_.y, a_, acc[15]);
        }

        if (d < DEPTH) {
            #pragma unroll
            for (int p = 0; p < PAR; ++p) {
                const int np = (int)((nodes >> (8 * p)) & 0xffULL);
                const unsigned long long nn = (unsigned long long)
                    (2 * np + 1 + (int)((pos >> REPLANE(p)) & 1ULL));
                nodes = (nodes & ~(0xffULL << (8 * p))) | (nn << (8 * p));
            }
        }
    }

    float* orow = out + (size_t)wave * DIM;
    *(float4*)(orow + lane * 8 + 0)       = make_float4(acc[0],  acc[1],  acc[2],  acc[3]);
    *(float4*)(orow + lane * 8 + 4)       = make_float4(acc[4],  acc[5],  acc[6],  acc[7]);
    *(float4*)(orow + 512 + lane * 8 + 0) = make_float4(acc[8],  acc[9],  acc[10], acc[11]);
    *(float4*)(orow + 512 + lane * 8 + 4) = make_float4(acc[12], acc[13], acc[14], acc[15]);
}

// ---------------------------------------------------------------------------
// Fallback (no workspace): fp32 gather both stages. Correct but slow.
// ---------------------------------------------------------------------------
__global__ __launch_bounds__(256) void fff_fallback_kernel(
    const float* __restrict__ x, const float* __restrict__ W_in,
    const float* __restrict__ b_in, const float* __restrict__ W_out,
    float* __restrict__ out, int B)
{
    const int wave = (int)((blockIdx.x * blockDim.x + threadIdx.x) >> 6);
    const int lane = (int)(threadIdx.x & 63);
    if (wave >= B) return;

    const float* xr = x + (size_t)wave * DIM;
    float4 x4[4];
    x4[0] = *(const float4*)(xr + lane * 8 + 0);
    x4[1] = *(const float4*)(xr + lane * 8 + 4);
    x4[2] = *(const float4*)(xr + 512 + lane * 8 + 0);
    x4[3] = *(const float4*)(xr + 512 + lane * 8 + 4);

    float acc[16];
    #pragma unroll
    for (int i = 0; i < 16; ++i) acc[i] = 0.f;
    int node[PAR];
    #pragma unroll
    for (int p = 0; p < PAR; ++p) node[p] = 0;

    for (int d = 0; d <= DEPTH; ++d) {
        #pragma unroll
        for (int p = 0; p < PAR; ++p) {
            const int gidx = p * N_NODES + node[p];
            const float* wr = W_in + (size_t)gidx * DIM;
            const float4 wa = *(const float4*)(wr + lane * 8 + 0);
            const float4 wb = *(const float4*)(wr + lane * 8 + 4);
            const float4 wc = *(const float4*)(wr + 512 + lane * 8 + 0);
            const float4 wd = *(const float4*)(wr + 512 + lane * 8 + 4);
            float s = 0.f;
            s = fmaf(x4[0].x, wa.x, s); s = fmaf(x4[0].y, wa.y, s);
            s = fmaf(x4[0].z, wa.z, s); s = fmaf(x4[0].w, wa.w, s);
            s = fmaf(x4[1].x, wb.x, s); s = fmaf(x4[1].y, wb.y, s);
            s = fmaf(x4[1].z, wb.z, s); s = fmaf(x4[1].w, wb.w, s);
            s = fmaf(x4[2].x, wc.x, s); s = fmaf(x4[2].y, wc.y, s);
            s = fmaf(x4[2].z, wc.z, s); s = fmaf(x4[2].w, wc.w, s);
            s = fmaf(x4[3].x, wd.x, s); s = fmaf(x4[3].y, wd.y, s);
            s = fmaf(x4[3].z, wd.z, s); s = fmaf(x4[3].w, wd.w, s);
            #pragma unroll
            for (int off = 32; off >= 1; off >>= 1)
                s += __shfl_xor(s, off, 64);
            const float logit = s + b_in[gidx];
            const float act = logit / (1.0f + __expf(-logit));
            #pragma unroll
            for (int k = 0; k < 2; ++k) {
                #pragma unroll
                for (int j = 0; j < 8; ++j) {
                    const int e = k * 512 + lane * 8 + j;
                    acc[k * 8 + j] = fmaf(act, W_out[(size_t)e * WIDTH + gidx], acc[k * 8 + j]);
                }
            }
            node[p] = 2 * node[p] + 1 + ((logit > 0.0f) ? 1 : 0);
        }
    }

    float* orow = out + (size_t)wave * DIM;
    *(float4*)(orow + lane * 8 + 0)       = make_float4(acc[0],  acc[1],  acc[2],  acc[3]);
    *(float4*)(orow + lane * 8 + 4)       = make_float4(acc[4],  acc[5],  acc[6],  acc[7]);
    *(float4*)(orow + 512 + lane * 8 + 0) = make_float4(acc[8],  acc[9],  acc[10], acc[11]);
    *(float4*)(orow + 512 + lane * 8 + 4) = make_float4(acc[12], acc[13], acc[14], acc[15]);
}

extern "C" void kernel_launch(void* const* d_in, const int* in_sizes, int n_in,
                              void* d_out, int out_size, void* d_ws, size_t ws_size,
                              hipStream_t stream) {
    const float* oldx  = (const float*)d_in[0];
    const float* W_in  = (const float*)d_in[1];
    const float* b_in  = (const float*)d_in[2];
    const float* W_out = (const float*)d_in[3];
    float* out = (float*)d_out;

    const int B = in_sizes[0] / DIM;   // 8192 rows

    const size_t half = (size_t)WIDTH * DIM * sizeof(unsigned short);  // 4.18 MB
    const bool use_lp = (ws_size >= 2 * half) && (d_ws != nullptr);

    const int blocks = (B + 3) / 4;    // 4 waves (256 threads) per block

    if (use_lp) {
        unsigned short* WoT = (unsigned short*)d_ws;
        unsigned int*   Wh  = (unsigned int*)((char*)d_ws + half);
        prep_kernel<<<TRANS_BLOCKS + 1024, 256, 0, stream>>>(W_out, W_in, WoT, Wh);
        fff_f16_kernel<<<blocks, 256, 0, stream>>>(oldx, W_in, b_in, Wh, WoT, out, B);
    } else {
        fff_fallback_kernel<<<blocks, 256, 0, stream>>>(oldx, W_in, b_in, W_out, out, B);
    }
}

// Round 4
// 187.124 us; speedup vs baseline: 2.7623x; 1.0894x over previous
//
#include <hip/hip_runtime.h>
#include <math.h>

#define DIM 1024
#define DEPTH 7
#define PAR 8
#define N_NODES 255   // 2^(DEPTH+1) - 1
#define WIDTH 2040    // PAR * N_NODES
// f16-dot error sigma ~3e-4; 0.01 is ~30 sigma.
#define MARGIN 0.01f

// lane that holds tree p's reduced logit after the fold network (bits 8/16/32)
#define REPLANE(p) ((((p) & 1) << 3) | ((((p) >> 1) & 1) << 4) | ((((p) >> 2) & 1) << 5))

// pin a uint4's components in VGPRs at this program point: forces the loaded
// values to be live-in-register here (single s_waitcnt covers the batch).
#define PIN4(u) asm volatile("" : "+v"((u).x), "+v"((u).y), "+v"((u).z), "+v"((u).w))

typedef _Float16 half2v __attribute__((ext_vector_type(2)));

__device__ __forceinline__ half2v as_h2(unsigned int u) {
    union { unsigned int u; half2v h; } c; c.u = u; return c.h;
}
__device__ __forceinline__ unsigned int pack_h2(float a, float b) {
    union { half2v h; unsigned int u; } c;
    c.h = (half2v){(_Float16)a, (_Float16)b};   // v_cvt_f16_f32 is RTNE
    return c.u;
}

// f16 dot2 with fp32 accumulate; builtin if available, exact fallback otherwise
__device__ __forceinline__ float dot2h(unsigned int a, unsigned int b, float c) {
#if __has_builtin(__builtin_amdgcn_fdot2)
    return __builtin_amdgcn_fdot2(as_h2(a), as_h2(b), c, false);
#else
    half2v ha = as_h2(a), hb = as_h2(b);
    c = fmaf((float)ha.x, (float)hb.x, c);
    return fmaf((float)ha.y, (float)hb.y, c);
#endif
}

// fold two per-lane partial sums into one register, separating them by lane bit K.
__device__ __forceinline__ float foldK(float a, float b, int K) {
    const bool hi = (threadIdx.x & (unsigned)K) != 0;
    const float keep = hi ? b : a;
    const float send = hi ? a : b;
    return keep + __shfl_xor(send, K, 64);
}

// ---------------------------------------------------------------------------
// Fused prep: blocks [0,512) transpose+convert W_out f32 [DIM][WIDTH] ->
// WoT f16 [WIDTH][DIM]; blocks [512,...) convert W_in f32 -> f16 packed.
// ---------------------------------------------------------------------------
#define TRANS_BLOCKS 512   // 32 (WIDTH/64 tiles) x 16 (DIM/64 tiles)

__global__ __launch_bounds__(256) void prep_kernel(
    const float* __restrict__ W_out,      // [DIM][WIDTH] f32
    const float* __restrict__ W_in,       // [WIDTH][DIM] f32
    unsigned short* __restrict__ WoT,     // [WIDTH][DIM] f16
    unsigned int* __restrict__ Wh)        // [WIDTH][DIM/2] f16-pair dwords
{
    __shared__ float tile[64][65];
    if (blockIdx.x < TRANS_BLOCKS) {
        const int w0 = (int)(blockIdx.x & 31) * 64;
        const int d0 = (int)(blockIdx.x >> 5) * 64;
        const int tid = (int)threadIdx.x;
        const int sub = tid & 15;
        const int grp = tid >> 4;

        #pragma unroll
        for (int pass = 0; pass < 4; ++pass) {
            const int dl = pass * 16 + grp;
            const int wl = sub * 4;
            const int w = w0 + wl;
            const int d = d0 + dl;
            float4 v = make_float4(0.f, 0.f, 0.f, 0.f);
            if (w + 3 < WIDTH) {
                v = *(const float4*)(W_out + (size_t)d * WIDTH + w);
            } else {
                float t0 = (w + 0 < WIDTH) ? W_out[(size_t)d * WIDTH + w + 0] : 0.f;
                float t1 = (w + 1 < WIDTH) ? W_out[(size_t)d * WIDTH + w + 1] : 0.f;
                float t2 = (w + 2 < WIDTH) ? W_out[(size_t)d * WIDTH + w + 2] : 0.f;
                float t3 = (w + 3 < WIDTH) ? W_out[(size_t)d * WIDTH + w + 3] : 0.f;
                v = make_float4(t0, t1, t2, t3);
            }
            tile[dl][wl + 0] = v.x; tile[dl][wl + 1] = v.y;
            tile[dl][wl + 2] = v.z; tile[dl][wl + 3] = v.w;
        }
        __syncthreads();
        #pragma unroll
        for (int pass = 0; pass < 4; ++pass) {
            const int wl = pass * 16 + grp;
            const int dl = sub * 4;
            const int w = w0 + wl;
            if (w < WIDTH) {
                uint2 pk;
                pk.x = pack_h2(tile[dl + 0][wl], tile[dl + 1][wl]);
                pk.y = pack_h2(tile[dl + 2][wl], tile[dl + 3][wl]);
                *(uint2*)(WoT + (size_t)w * DIM + d0 + dl) = pk;
            }
        }
    } else {
        const int n4 = WIDTH * DIM / 4;
        const int nthr = ((int)gridDim.x - TRANS_BLOCKS) * 256;
        for (int i = ((int)blockIdx.x - TRANS_BLOCKS) * 256 + (int)threadIdx.x;
             i < n4; i += nthr) {
            float4 v = ((const float4*)W_in)[i];
            uint2 pk;
            pk.x = pack_h2(v.x, v.y);
            pk.y = pack_h2(v.z, v.w);
            ((uint2*)Wh)[i] = pk;
        }
    }
}

// ---------------------------------------------------------------------------
// Main kernel: one wave per row. Exactly ONE pinned batch (the Phase-C WoT
// loads): issued at the top of each level (sched_barrier keeps them there),
// consumed after silu -- their latency hides under Phase A + fold + repair.
// Phase A stays per-tree streaming (the verified 105us behavior). Peak
// pressure ~116 VGPR -> same 4-wave/SIMD tier as the 72-VGPR baseline.
// ---------------------------------------------------------------------------
__global__ __launch_bounds__(256) void fff_f16_kernel(
    const float* __restrict__ x,            // [B, DIM] f32
    const float* __restrict__ W_in,         // [WIDTH, DIM] f32 (repair only)
    const float* __restrict__ b_in,         // [WIDTH] f32
    const unsigned int* __restrict__ Wh,    // f16 W_in  [WIDTH][DIM/2] dwords
    const unsigned short* __restrict__ WoT, // f16 W_out^T [WIDTH][DIM]
    float* __restrict__ out,                // [B, DIM] f32
    int B)
{
    const int wave = (int)((blockIdx.x * blockDim.x + threadIdx.x) >> 6);
    const int lane = (int)(threadIdx.x & 63);
    if (wave >= B) return;

    const float* xr = x + (size_t)wave * DIM;
    unsigned int xp[8];
    {
        float4 a0 = *(const float4*)(xr + lane * 8 + 0);
        float4 a1 = *(const float4*)(xr + lane * 8 + 4);
        float4 a2 = *(const float4*)(xr + 512 + lane * 8 + 0);
        float4 a3 = *(const float4*)(xr + 512 + lane * 8 + 4);
        xp[0] = pack_h2(a0.x, a0.y);
        xp[1] = pack_h2(a0.z, a0.w);
        xp[2] = pack_h2(a1.x, a1.y);
        xp[3] = pack_h2(a1.z, a1.w);
        xp[4] = pack_h2(a2.x, a2.y);
        xp[5] = pack_h2(a2.z, a2.w);
        xp[6] = pack_h2(a3.x, a3.y);
        xp[7] = pack_h2(a3.z, a3.w);
    }

    float acc[16];
    #pragma unroll
    for (int i = 0; i < 16; ++i) acc[i] = 0.f;

    unsigned long long nodes = 0ULL;   // 8 x u8 node indices (all < 255)
    const int myp = ((lane >> 3) & 1) | (((lane >> 4) & 1) << 1) | (((lane >> 5) & 1) << 2);

    #pragma unroll 1
    for (int d = 0; d <= DEPTH; ++d) {
        int gidx[PAR];
        #pragma unroll
        for (int p = 0; p < PAR; ++p) {
            const int np = (int)((nodes >> (8 * p)) & 0xffULL);
            gidx[p] = p * N_NODES + np;
        }

        // bias gather: index is dot-independent -> issue before Phase A
        const int ga = (lane & 8) ? gidx[1] : gidx[0];
        const int gb = (lane & 8) ? gidx[3] : gidx[2];
        const int gc = (lane & 8) ? gidx[5] : gidx[4];
        const int gd = (lane & 8) ? gidx[7] : gidx[6];
        const int ge = (lane & 16) ? gb : ga;
        const int gf = (lane & 16) ? gd : gc;
        const int gmine = (lane & 32) ? gf : ge;
        const float bias = b_in[gmine];

        // Phase-C loads issued FIRST: latency hides under everything below.
        uint4 wv0[PAR], wv1[PAR];
        #pragma unroll
        for (int p = 0; p < PAR; ++p) {
            const unsigned short* wo = WoT + (size_t)gidx[p] * DIM;
            wv0[p] = *(const uint4*)(wo + lane * 8);
            wv1[p] = *(const uint4*)(wo + 512 + lane * 8);
        }
        // Don't let the scheduler sink these loads into Phase C.
        __builtin_amdgcn_sched_barrier(0);

        // Phase A: per-tree load + dot (small transient; scheduler pipelines
        // across the 8 independent trees, TLP covers the rest)
        float partial[PAR];
        #pragma unroll
        for (int p = 0; p < PAR; ++p) {
            const unsigned int* wr = Wh + (size_t)gidx[p] * (DIM / 2);
            const uint4 u0 = *(const uint4*)(wr + lane * 4);
            const uint4 u1 = *(const uint4*)(wr + 256 + lane * 4);
            float s = 0.f;
            s = dot2h(xp[0], u0.x, s);
            s = dot2h(xp[1], u0.y, s);
            s = dot2h(xp[2], u0.z, s);
            s = dot2h(xp[3], u0.w, s);
            s = dot2h(xp[4], u1.x, s);
            s = dot2h(xp[5], u1.y, s);
            s = dot2h(xp[6], u1.z, s);
            s = dot2h(xp[7], u1.w, s);
            partial[p] = s;
        }

        // Phase B: fold network over lane bits {8,16,32}, butterfly over {1,2,4}
        const float c01 = foldK(partial[0], partial[1], 8);
        const float c23 = foldK(partial[2], partial[3], 8);
        const float c45 = foldK(partial[4], partial[5], 8);
        const float c67 = foldK(partial[6], partial[7], 8);
        const float d0f = foldK(c01, c23, 16);
        const float d1f = foldK(c45, c67, 16);
        float e = foldK(d0f, d1f, 32);
        e += __shfl_xor(e, 1, 64);
        e += __shfl_xor(e, 2, 64);
        e += __shfl_xor(e, 4, 64);
        float my = e + bias;

        // Repair: near-zero logits recomputed in fp32 (decisions must match
        // numpy). Recomputes gi from `nodes` so gidx[] can die after load
        // issue; pairwise float4 keeps transient pressure low (cold branch).
        if (d < DEPTH) {
            const unsigned long long bal = __ballot(fabsf(my) < MARGIN);
            unsigned rm = 0;
            #pragma unroll
            for (int p = 0; p < PAR; ++p)
                rm |= ((unsigned)((bal >> REPLANE(p)) & 1ULL)) << p;
            if (rm) {
                while (rm) {
                    const int p = __builtin_ctz(rm); rm &= (rm - 1u);
                    const int np = (int)((nodes >> (8 * p)) & 0xffULL);
                    const int gi = p * N_NODES + np;
                    const float* wr = W_in + (size_t)gi * DIM;
                    float s = 0.f;
                    #pragma unroll
                    for (int q = 0; q < 4; ++q) {
                        const int off = (q & 1) * 4 + (q >> 1) * 512 + lane * 8;
                        const float4 fx = *(const float4*)(xr + off);
                        const float4 fw = *(const float4*)(wr + off);
                        s = fmaf(fx.x, fw.x, s); s = fmaf(fx.y, fw.y, s);
                        s = fmaf(fx.z, fw.z, s); s = fmaf(fx.w, fw.w, s);
                    }
                    #pragma unroll
                    for (int off = 32; off >= 1; off >>= 1)
                        s += __shfl_xor(s, off, 64);
                    const float lf = s + b_in[gi];
                    my = (myp == p) ? lf : my;
                }
            }
        }

        // per-lane silu (8 trees in parallel), decisions via one ballot
        const float act_mine = my / (1.0f + __expf(-my));
        const unsigned long long pos = __ballot(my > 0.0f);

        float act[PAR];
        #pragma unroll
        for (int p = 0; p < PAR; ++p)
            act[p] = __shfl(act_mine, REPLANE(p), 64);

        // Pin the C batch: all 16 loads complete here (one wait); the FMA
        // chain below runs waitless.
        #pragma unroll
        for (int p = 0; p < PAR; ++p) { PIN4(wv0[p]); PIN4(wv1[p]); }

        // Phase C: f16 axpy into fp32 acc (v_fma_mix pattern)
        #pragma unroll
        for (int p = 0; p < PAR; ++p) {
            const float a_ = act[p];
            half2v h_;
            h_ = as_h2(wv0[p].x); acc[0]  = fmaf((float)h_.x, a_, acc[0]);  acc[1]  = fmaf((float)h_.y, a_, acc[1]);
            h_ = as_h2(wv0[p].y); acc[2]  = fmaf((float)h_.x, a_, acc[2]);  acc[3]  = fmaf((float)h_.y, a_, acc[3]);
            h_ = as_h2(wv0[p].z); acc[4]  = fmaf((float)h_.x, a_, acc[4]);  acc[5]  = fmaf((float)h_.y, a_, acc[5]);
            h_ = as_h2(wv0[p].w); acc[6]  = fmaf((float)h_.x, a_, acc[6]);  acc[7]  = fmaf((float)h_.y, a_, acc[7]);
            h_ = as_h2(wv1[p].x); acc[8]  = fmaf((float)h_.x, a_, acc[8]);  acc[9]  = fmaf((float)h_.y, a_, acc[9]);
            h_ = as_h2(wv1[p].y); acc[10] = fmaf((float)h_.x, a_, acc[10]); acc[11] = fmaf((float)h_.y, a_, acc[11]);
            h_ = as_h2(wv1[p].z); acc[12] = fmaf((float)h_.x, a_, acc[12]); acc[13] = fmaf((float)h_.y, a_, acc[13]);
            h_ = as_h2(wv1[p].w); acc[14] = fmaf((float)h_.x, a_, acc[14]); acc[15] = fmaf((float)h_.y, a_, acc[15]);
        }

        if (d < DEPTH) {
            #pragma unroll
            for (int p = 0; p < PAR; ++p) {
                const int np = (int)((nodes >> (8 * p)) & 0xffULL);
                const unsigned long long nn = (unsigned long long)
                    (2 * np + 1 + (int)((pos >> REPLANE(p)) & 1ULL));
                nodes = (nodes & ~(0xffULL << (8 * p))) | (nn << (8 * p));
            }
        }
    }

    float* orow = out + (size_t)wave * DIM;
    *(float4*)(orow + lane * 8 + 0)       = make_float4(acc[0],  acc[1],  acc[2],  acc[3]);
    *(float4*)(orow + lane * 8 + 4)       = make_float4(acc[4],  acc[5],  acc[6],  acc[7]);
    *(float4*)(orow + 512 + lane * 8 + 0) = make_float4(acc[8],  acc[9],  acc[10], acc[11]);
    *(float4*)(orow + 512 + lane * 8 + 4) = make_float4(acc[12], acc[13], acc[14], acc[15]);
}

// ---------------------------------------------------------------------------
// Fallback (no workspace): fp32 gather both stages. Correct but slow.
// ---------------------------------------------------------------------------
__global__ __launch_bounds__(256) void fff_fallback_kernel(
    const float* __restrict__ x, const float* __restrict__ W_in,
    const float* __restrict__ b_in, const float* __restrict__ W_out,
    float* __restrict__ out, int B)
{
    const int wave = (int)((blockIdx.x * blockDim.x + threadIdx.x) >> 6);
    const int lane = (int)(threadIdx.x & 63);
    if (wave >= B) return;

    const float* xr = x + (size_t)wave * DIM;
    float4 x4[4];
    x4[0] = *(const float4*)(xr + lane * 8 + 0);
    x4[1] = *(const float4*)(xr + lane * 8 + 4);
    x4[2] = *(const float4*)(xr + 512 + lane * 8 + 0);
    x4[3] = *(const float4*)(xr + 512 + lane * 8 + 4);

    float acc[16];
    #pragma unroll
    for (int i = 0; i < 16; ++i) acc[i] = 0.f;
    int node[PAR];
    #pragma unroll
    for (int p = 0; p < PAR; ++p) node[p] = 0;

    for (int d = 0; d <= DEPTH; ++d) {
        #pragma unroll
        for (int p = 0; p < PAR; ++p) {
            const int gidx = p * N_NODES + node[p];
            const float* wr = W_in + (size_t)gidx * DIM;
            const float4 wa = *(const float4*)(wr + lane * 8 + 0);
            const float4 wb = *(const float4*)(wr + lane * 8 + 4);
            const float4 wc = *(const float4*)(wr + 512 + lane * 8 + 0);
            const float4 wd = *(const float4*)(wr + 512 + lane * 8 + 4);
            float s = 0.f;
            s = fmaf(x4[0].x, wa.x, s); s = fmaf(x4[0].y, wa.y, s);
            s = fmaf(x4[0].z, wa.z, s); s = fmaf(x4[0].w, wa.w, s);
            s = fmaf(x4[1].x, wb.x, s); s = fmaf(x4[1].y, wb.y, s);
            s = fmaf(x4[1].z, wb.z, s); s = fmaf(x4[1].w, wb.w, s);
            s = fmaf(x4[2].x, wc.x, s); s = fmaf(x4[2].y, wc.y, s);
            s = fmaf(x4[2].z, wc.z, s); s = fmaf(x4[2].w, wc.w, s);
            s = fmaf(x4[3].x, wd.x, s); s = fmaf(x4[3].y, wd.y, s);
            s = fmaf(x4[3].z, wd.z, s); s = fmaf(x4[3].w, wd.w, s);
            #pragma unroll
            for (int off = 32; off >= 1; off >>= 1)
                s += __shfl_xor(s, off, 64);
            const float logit = s + b_in[gidx];
            const float act = logit / (1.0f + __expf(-logit));
            #pragma unroll
            for (int k = 0; k < 2; ++k) {
                #pragma unroll
                for (int j = 0; j < 8; ++j) {
                    const int e = k * 512 + lane * 8 + j;
                    acc[k * 8 + j] = fmaf(act, W_out[(size_t)e * WIDTH + gidx], acc[k * 8 + j]);
                }
            }
            node[p] = 2 * node[p] + 1 + ((logit > 0.0f) ? 1 : 0);
        }
    }

    float* orow = out + (size_t)wave * DIM;
    *(float4*)(orow + lane * 8 + 0)       = make_float4(acc[0],  acc[1],  acc[2],  acc[3]);
    *(float4*)(orow + lane * 8 + 4)       = make_float4(acc[4],  acc[5],  acc[6],  acc[7]);
    *(float4*)(orow + 512 + lane * 8 + 0) = make_float4(acc[8],  acc[9],  acc[10], acc[11]);
    *(float4*)(orow + 512 + lane * 8 + 4) = make_float4(acc[12], acc[13], acc[14], acc[15]);
}

extern "C" void kernel_launch(void* const* d_in, const int* in_sizes, int n_in,
                              void* d_out, int out_size, void* d_ws, size_t ws_size,
                              hipStream_t stream) {
    const float* oldx  = (const float*)d_in[0];
    const float* W_in  = (const float*)d_in[1];
    const float* b_in  = (const float*)d_in[2];
    const float* W_out = (const float*)d_in[3];
    float* out = (float*)d_out;

    const int B = in_sizes[0] / DIM;   // 8192 rows

    const size_t half = (size_t)WIDTH * DIM * sizeof(unsigned short);  // 4.18 MB
    const bool use_lp = (ws_size >= 2 * half) && (d_ws != nullptr);

    const int blocks = (B + 3) / 4;    // 4 waves (256 threads) per block

    if (use_lp) {
        unsigned short* WoT = (unsigned short*)d_ws;
        unsigned int*   Wh  = (unsigned int*)((char*)d_ws + half);
        prep_kernel<<<TRANS_BLOCKS + 1024, 256, 0, stream>>>(W_out, W_in, WoT, Wh);
        fff_f16_kernel<<<blocks, 256, 0, stream>>>(oldx, W_in, b_in, Wh, WoT, out, B);
    } else {
        fff_fallback_kernel<<<blocks, 256, 0, stream>>>(oldx, W_in, b_in, W_out, out, B);
    }
}

// Round 5
// 181.134 us; speedup vs baseline: 2.8536x; 1.0331x over previous
//
#include <hip/hip_runtime.h>
#include <math.h>

#define DIM 1024
#define DEPTH 7
#define PAR 8
#define N_NODES 255   // 2^(DEPTH+1) - 1
#define WIDTH 2040    // PAR * N_NODES
// f16-dot error sigma ~3e-4; 0.01 is ~30 sigma.
#define MARGIN 0.01f

// lane that holds tree p's reduced logit after the fold network (bits 8/16/32)
#define REPLANE(p) ((((p) & 1) << 3) | ((((p) >> 1) & 1) << 4) | ((((p) >> 2) & 1) << 5))

typedef _Float16 half2v __attribute__((ext_vector_type(2)));

__device__ __forceinline__ half2v as_h2(unsigned int u) {
    union { unsigned int u; half2v h; } c; c.u = u; return c.h;
}
__device__ __forceinline__ unsigned int pack_h2(float a, float b) {
    union { half2v h; unsigned int u; } c;
    c.h = (half2v){(_Float16)a, (_Float16)b};   // v_cvt_f16_f32 is RTNE
    return c.u;
}

// f16 dot2 with fp32 accumulate; builtin if available, exact fallback otherwise
__device__ __forceinline__ float dot2h(unsigned int a, unsigned int b, float c) {
#if __has_builtin(__builtin_amdgcn_fdot2)
    return __builtin_amdgcn_fdot2(as_h2(a), as_h2(b), c, false);
#else
    half2v ha = as_h2(a), hb = as_h2(b);
    c = fmaf((float)ha.x, (float)hb.x, c);
    return fmaf((float)ha.y, (float)hb.y, c);
#endif
}

// fold two per-lane partial sums into one register, separating them by lane bit K.
__device__ __forceinline__ float foldK(float a, float b, int K) {
    const bool hi = (threadIdx.x & (unsigned)K) != 0;
    const float keep = hi ? b : a;
    const float send = hi ? a : b;
    return keep + __shfl_xor(send, K, 64);
}

// ---------------------------------------------------------------------------
// Fused prep: blocks [0,512) transpose+convert W_out f32 [DIM][WIDTH] ->
// WoT f16 [WIDTH][DIM]; blocks [512,...) convert W_in f32 -> f16 packed.
// ---------------------------------------------------------------------------
#define TRANS_BLOCKS 512   // 32 (WIDTH/64 tiles) x 16 (DIM/64 tiles)

__global__ __launch_bounds__(256) void prep_kernel(
    const float* __restrict__ W_out,      // [DIM][WIDTH] f32
    const float* __restrict__ W_in,       // [WIDTH][DIM] f32
    unsigned short* __restrict__ WoT,     // [WIDTH][DIM] f16
    unsigned int* __restrict__ Wh)        // [WIDTH][DIM/2] f16-pair dwords
{
    __shared__ float tile[64][65];
    if (blockIdx.x < TRANS_BLOCKS) {
        const int w0 = (int)(blockIdx.x & 31) * 64;
        const int d0 = (int)(blockIdx.x >> 5) * 64;
        const int tid = (int)threadIdx.x;
        const int sub = tid & 15;
        const int grp = tid >> 4;

        #pragma unroll
        for (int pass = 0; pass < 4; ++pass) {
            const int dl = pass * 16 + grp;
            const int wl = sub * 4;
            const int w = w0 + wl;
            const int d = d0 + dl;
            float4 v = make_float4(0.f, 0.f, 0.f, 0.f);
            if (w + 3 < WIDTH) {
                v = *(const float4*)(W_out + (size_t)d * WIDTH + w);
            } else {
                float t0 = (w + 0 < WIDTH) ? W_out[(size_t)d * WIDTH + w + 0] : 0.f;
                float t1 = (w + 1 < WIDTH) ? W_out[(size_t)d * WIDTH + w + 1] : 0.f;
                float t2 = (w + 2 < WIDTH) ? W_out[(size_t)d * WIDTH + w + 2] : 0.f;
                float t3 = (w + 3 < WIDTH) ? W_out[(size_t)d * WIDTH + w + 3] : 0.f;
                v = make_float4(t0, t1, t2, t3);
            }
            tile[dl][wl + 0] = v.x; tile[dl][wl + 1] = v.y;
            tile[dl][wl + 2] = v.z; tile[dl][wl + 3] = v.w;
        }
        __syncthreads();
        #pragma unroll
        for (int pass = 0; pass < 4; ++pass) {
            const int wl = pass * 16 + grp;
            const int dl = sub * 4;
            const int w = w0 + wl;
            if (w < WIDTH) {
                uint2 pk;
                pk.x = pack_h2(tile[dl + 0][wl], tile[dl + 1][wl]);
                pk.y = pack_h2(tile[dl + 2][wl], tile[dl + 3][wl]);
                *(uint2*)(WoT + (size_t)w * DIM + d0 + dl) = pk;
            }
        }
    } else {
        const int n4 = WIDTH * DIM / 4;
        const int nthr = ((int)gridDim.x - TRANS_BLOCKS) * 256;
        for (int i = ((int)blockIdx.x - TRANS_BLOCKS) * 256 + (int)threadIdx.x;
             i < n4; i += nthr) {
            float4 v = ((const float4*)W_in)[i];
            uint2 pk;
            pk.x = pack_h2(v.x, v.y);
            pk.y = pack_h2(v.z, v.w);
            ((uint2*)Wh)[i] = pk;
        }
    }
}

// ---------------------------------------------------------------------------
// Stage 1: traversal only. Working set = Wh (4.2 MB) ~ one XCD L2.
// Per row emits 64 (gidx u16, act f32) records (level-major, tree-minor).
// ---------------------------------------------------------------------------
__global__ __launch_bounds__(256) void fff_stage1_kernel(
    const float* __restrict__ x,            // [B, DIM] f32
    const float* __restrict__ W_in,         // [WIDTH, DIM] f32 (repair only)
    const float* __restrict__ b_in,         // [WIDTH] f32
    const unsigned int* __restrict__ Wh,    // f16 W_in [WIDTH][DIM/2] dwords
    float* __restrict__ acts,               // [B][64] f32
    unsigned short* __restrict__ gidx_out,  // [B][64] u16
    int B)
{
    const int wave = (int)((blockIdx.x * blockDim.x + threadIdx.x) >> 6);
    const int lane = (int)(threadIdx.x & 63);
    if (wave >= B) return;

    const float* xr = x + (size_t)wave * DIM;
    unsigned int xp[8];
    {
        float4 a0 = *(const float4*)(xr + lane * 8 + 0);
        float4 a1 = *(const float4*)(xr + lane * 8 + 4);
        float4 a2 = *(const float4*)(xr + 512 + lane * 8 + 0);
        float4 a3 = *(const float4*)(xr + 512 + lane * 8 + 4);
        xp[0] = pack_h2(a0.x, a0.y);
        xp[1] = pack_h2(a0.z, a0.w);
        xp[2] = pack_h2(a1.x, a1.y);
        xp[3] = pack_h2(a1.z, a1.w);
        xp[4] = pack_h2(a2.x, a2.y);
        xp[5] = pack_h2(a2.z, a2.w);
        xp[6] = pack_h2(a3.x, a3.y);
        xp[7] = pack_h2(a3.z, a3.w);
    }

    unsigned long long nodes = 0ULL;   // 8 x u8 node indices (all < 255)
    const int myp = ((lane >> 3) & 1) | (((lane >> 4) & 1) << 1) | (((lane >> 5) & 1) << 2);

    #pragma unroll 1
    for (int d = 0; d <= DEPTH; ++d) {
        int gidx[PAR];
        #pragma unroll
        for (int p = 0; p < PAR; ++p) {
            const int np = (int)((nodes >> (8 * p)) & 0xffULL);
            gidx[p] = p * N_NODES + np;
        }

        // per-lane owned node index (lane 8p owns tree p) + its bias
        const int ga = (lane & 8) ? gidx[1] : gidx[0];
        const int gb = (lane & 8) ? gidx[3] : gidx[2];
        const int gc = (lane & 8) ? gidx[5] : gidx[4];
        const int gd = (lane & 8) ? gidx[7] : gidx[6];
        const int ge = (lane & 16) ? gb : ga;
        const int gf = (lane & 16) ? gd : gc;
        const int gmine = (lane & 32) ? gf : ge;
        const float bias = b_in[gmine];

        // Phase A: per-tree load + dot (streaming; TLP hides latency)
        float partial[PAR];
        #pragma unroll
        for (int p = 0; p < PAR; ++p) {
            const unsigned int* wr = Wh + (size_t)gidx[p] * (DIM / 2);
            const uint4 u0 = *(const uint4*)(wr + lane * 4);
            const uint4 u1 = *(const uint4*)(wr + 256 + lane * 4);
            float s = 0.f;
            s = dot2h(xp[0], u0.x, s);
            s = dot2h(xp[1], u0.y, s);
            s = dot2h(xp[2], u0.z, s);
            s = dot2h(xp[3], u0.w, s);
            s = dot2h(xp[4], u1.x, s);
            s = dot2h(xp[5], u1.y, s);
            s = dot2h(xp[6], u1.z, s);
            s = dot2h(xp[7], u1.w, s);
            partial[p] = s;
        }

        // Phase B: fold network over lane bits {8,16,32}, butterfly over {1,2,4}
        const float c01 = foldK(partial[0], partial[1], 8);
        const float c23 = foldK(partial[2], partial[3], 8);
        const float c45 = foldK(partial[4], partial[5], 8);
        const float c67 = foldK(partial[6], partial[7], 8);
        const float d0f = foldK(c01, c23, 16);
        const float d1f = foldK(c45, c67, 16);
        float e = foldK(d0f, d1f, 32);
        e += __shfl_xor(e, 1, 64);
        e += __shfl_xor(e, 2, 64);
        e += __shfl_xor(e, 4, 64);
        float my = e + bias;

        // Repair: near-zero logits recomputed in fp32 (decisions must match numpy)
        if (d < DEPTH) {
            const unsigned long long bal = __ballot(fabsf(my) < MARGIN);
            unsigned rm = 0;
            #pragma unroll
            for (int p = 0; p < PAR; ++p)
                rm |= ((unsigned)((bal >> REPLANE(p)) & 1ULL)) << p;
            if (rm) {
                while (rm) {
                    const int p = __builtin_ctz(rm); rm &= (rm - 1u);
                    const int np = (int)((nodes >> (8 * p)) & 0xffULL);
                    const int gi = p * N_NODES + np;
                    const float* wr = W_in + (size_t)gi * DIM;
                    float s = 0.f;
                    #pragma unroll
                    for (int q = 0; q < 4; ++q) {
                        const int off = (q & 1) * 4 + (q >> 1) * 512 + lane * 8;
                        const float4 fx = *(const float4*)(xr + off);
                        const float4 fw = *(const float4*)(wr + off);
                        s = fmaf(fx.x, fw.x, s); s = fmaf(fx.y, fw.y, s);
                        s = fmaf(fx.z, fw.z, s); s = fmaf(fx.w, fw.w, s);
                    }
                    #pragma unroll
                    for (int off = 32; off >= 1; off >>= 1)
                        s += __shfl_xor(s, off, 64);
                    const float lf = s + b_in[gi];
                    my = (myp == p) ? lf : my;
                }
            }
        }

        // per-lane silu; decisions via one ballot
        const float act_mine = my / (1.0f + __expf(-my));
        const unsigned long long pos = __ballot(my > 0.0f);

        // lanes 0,8,...,56 own trees 0..7: emit (gidx, act) record
        if ((lane & 7) == 0) {
            const int slot = (wave << 6) + (d << 3) + myp;
            acts[slot] = act_mine;
            gidx_out[slot] = (unsigned short)gmine;
        }

        if (d < DEPTH) {
            #pragma unroll
            for (int p = 0; p < PAR; ++p) {
                const int np = (int)((nodes >> (8 * p)) & 0xffULL);
                const unsigned long long nn = (unsigned long long)
                    (2 * np + 1 + (int)((pos >> REPLANE(p)) & 1ULL));
                nodes = (nodes & ~(0xffULL << (8 * p))) | (nn << (8 * p));
            }
        }
    }
}

// ---------------------------------------------------------------------------
// Stage 2: gather-axpy. Working set = WoT (4.2 MB) ~ one XCD L2.
// One wave per row; 64 independent (act, gidx) axpy iterations -> deep MLP.
// ---------------------------------------------------------------------------
__global__ __launch_bounds__(256) void fff_stage2_kernel(
    const float* __restrict__ acts,          // [B][64] f32
    const unsigned short* __restrict__ gidx16, // [B][64] u16
    const unsigned short* __restrict__ WoT,  // f16 W_out^T [WIDTH][DIM]
    float* __restrict__ out,                 // [B, DIM] f32
    int B)
{
    const int wave = (int)((blockIdx.x * blockDim.x + threadIdx.x) >> 6);
    const int lane = (int)(threadIdx.x & 63);
    if (wave >= B) return;

    const int base = wave << 6;
    const float a_l = acts[base + lane];         // lane e holds record e
    const int   g_l = (int)gidx16[base + lane];

    float acc[16];
    #pragma unroll
    for (int i = 0; i < 16; ++i) acc[i] = 0.f;

    #pragma unroll 4
    for (int e = 0; e < 64; ++e) {
        const float a_ = __shfl(a_l, e, 64);
        const int   g  = __shfl(g_l, e, 64);
        const unsigned short* wo = WoT + (size_t)g * DIM;
        const uint4 u0 = *(const uint4*)(wo + lane * 8);
        const uint4 u1 = *(const uint4*)(wo + 512 + lane * 8);
        half2v h_;
        h_ = as_h2(u0.x); acc[0]  = fmaf((float)h_.x, a_, acc[0]);  acc[1]  = fmaf((float)h_.y, a_, acc[1]);
        h_ = as_h2(u0.y); acc[2]  = fmaf((float)h_.x, a_, acc[2]);  acc[3]  = fmaf((float)h_.y, a_, acc[3]);
        h_ = as_h2(u0.z); acc[4]  = fmaf((float)h_.x, a_, acc[4]);  acc[5]  = fmaf((float)h_.y, a_, acc[5]);
        h_ = as_h2(u0.w); acc[6]  = fmaf((float)h_.x, a_, acc[6]);  acc[7]  = fmaf((float)h_.y, a_, acc[7]);
        h_ = as_h2(u1.x); acc[8]  = fmaf((float)h_.x, a_, acc[8]);  acc[9]  = fmaf((float)h_.y, a_, acc[9]);
        h_ = as_h2(u1.y); acc[10] = fmaf((float)h_.x, a_, acc[10]); acc[11] = fmaf((float)h_.y, a_, acc[11]);
        h_ = as_h2(u1.z); acc[12] = fmaf((float)h_.x, a_, acc[12]); acc[13] = fmaf((float)h_.y, a_, acc[13]);
        h_ = as_h2(u1.w); acc[14] = fmaf((float)h_.x, a_, acc[14]); acc[15] = fmaf((float)h_.y, a_, acc[15]);
    }

    float* orow = out + (size_t)wave * DIM;
    *(float4*)(orow + lane * 8 + 0)       = make_float4(acc[0],  acc[1],  acc[2],  acc[3]);
    *(float4*)(orow + lane * 8 + 4)       = make_float4(acc[4],  acc[5],  acc[6],  acc[7]);
    *(float4*)(orow + 512 + lane * 8 + 0) = make_float4(acc[8],  acc[9],  acc[10], acc[11]);
    *(float4*)(orow + 512 + lane * 8 + 4) = make_float4(acc[12], acc[13], acc[14], acc[15]);
}

// ---------------------------------------------------------------------------
// Fused single-kernel path (verified r4 version) -- used if workspace is too
// small for the split intermediates but fits the f16 weight tables.
// ---------------------------------------------------------------------------
__global__ __launch_bounds__(256) void fff_f16_kernel(
    const float* __restrict__ x,
    const float* __restrict__ W_in,
    const float* __restrict__ b_in,
    const unsigned int* __restrict__ Wh,
    const unsigned short* __restrict__ WoT,
    float* __restrict__ out,
    int B)
{
    const int wave = (int)((blockIdx.x * blockDim.x + threadIdx.x) >> 6);
    const int lane = (int)(threadIdx.x & 63);
    if (wave >= B) return;

    const float* xr = x + (size_t)wave * DIM;
    unsigned int xp[8];
    {
        float4 a0 = *(const float4*)(xr + lane * 8 + 0);
        float4 a1 = *(const float4*)(xr + lane * 8 + 4);
        float4 a2 = *(const float4*)(xr + 512 + lane * 8 + 0);
        float4 a3 = *(const float4*)(xr + 512 + lane * 8 + 4);
        xp[0] = pack_h2(a0.x, a0.y);
        xp[1] = pack_h2(a0.z, a0.w);
        xp[2] = pack_h2(a1.x, a1.y);
        xp[3] = pack_h2(a1.z, a1.w);
        xp[4] = pack_h2(a2.x, a2.y);
        xp[5] = pack_h2(a2.z, a2.w);
        xp[6] = pack_h2(a3.x, a3.y);
        xp[7] = pack_h2(a3.z, a3.w);
    }

    float acc[16];
    #pragma unroll
    for (int i = 0; i < 16; ++i) acc[i] = 0.f;

    unsigned long long nodes = 0ULL;
    const int myp = ((lane >> 3) & 1) | (((lane >> 4) & 1) << 1) | (((lane >> 5) & 1) << 2);

    #pragma unroll 1
    for (int d = 0; d <= DEPTH; ++d) {
        int gidx[PAR];
        #pragma unroll
        for (int p = 0; p < PAR; ++p) {
            const int np = (int)((nodes >> (8 * p)) & 0xffULL);
            gidx[p] = p * N_NODES + np;
        }

        const int ga = (lane & 8) ? gidx[1] : gidx[0];
        const int gb = (lane & 8) ? gidx[3] : gidx[2];
        const int gc = (lane & 8) ? gidx[5] : gidx[4];
        const int gd = (lane & 8) ? gidx[7] : gidx[6];
        const int ge = (lane & 16) ? gb : ga;
        const int gf = (lane & 16) ? gd : gc;
        const int gmine = (lane & 32) ? gf : ge;
        const float bias = b_in[gmine];

        float partial[PAR];
        #pragma unroll
        for (int p = 0; p < PAR; ++p) {
            const unsigned int* wr = Wh + (size_t)gidx[p] * (DIM / 2);
            const uint4 u0 = *(const uint4*)(wr + lane * 4);
            const uint4 u1 = *(const uint4*)(wr + 256 + lane * 4);
            float s = 0.f;
            s = dot2h(xp[0], u0.x, s);
            s = dot2h(xp[1], u0.y, s);
            s = dot2h(xp[2], u0.z, s);
            s = dot2h(xp[3], u0.w, s);
            s = dot2h(xp[4], u1.x, s);
            s = dot2h(xp[5], u1.y, s);
            s = dot2h(xp[6], u1.z, s);
            s = dot2h(xp[7], u1.w, s);
            partial[p] = s;
        }

        const float c01 = foldK(partial[0], partial[1], 8);
        const float c23 = foldK(partial[2], partial[3], 8);
        const float c45 = foldK(partial[4], partial[5], 8);
        const float c67 = foldK(partial[6], partial[7], 8);
        const float d0f = foldK(c01, c23, 16);
        const float d1f = foldK(c45, c67, 16);
        float e = foldK(d0f, d1f, 32);
        e += __shfl_xor(e, 1, 64);
        e += __shfl_xor(e, 2, 64);
        e += __shfl_xor(e, 4, 64);
        float my = e + bias;

        if (d < DEPTH) {
            const unsigned long long bal = __ballot(fabsf(my) < MARGIN);
            unsigned rm = 0;
            #pragma unroll
            for (int p = 0; p < PAR; ++p)
                rm |= ((unsigned)((bal >> REPLANE(p)) & 1ULL)) << p;
            if (rm) {
                while (rm) {
                    const int p = __builtin_ctz(rm); rm &= (rm - 1u);
                    const int np = (int)((nodes >> (8 * p)) & 0xffULL);
                    const int gi = p * N_NODES + np;
                    const float* wr = W_in + (size_t)gi * DIM;
                    float s = 0.f;
                    #pragma unroll
                    for (int q = 0; q < 4; ++q) {
                        const int off = (q & 1) * 4 + (q >> 1) * 512 + lane * 8;
                        const float4 fx = *(const float4*)(xr + off);
                        const float4 fw = *(const float4*)(wr + off);
                        s = fmaf(fx.x, fw.x, s); s = fmaf(fx.y, fw.y, s);
                        s = fmaf(fx.z, fw.z, s); s = fmaf(fx.w, fw.w, s);
                    }
                    #pragma unroll
                    for (int off = 32; off >= 1; off >>= 1)
                        s += __shfl_xor(s, off, 64);
                    const float lf = s + b_in[gi];
                    my = (myp == p) ? lf : my;
                }
            }
        }

        const float act_mine = my / (1.0f + __expf(-my));
        const unsigned long long pos = __ballot(my > 0.0f);

        float act[PAR];
        #pragma unroll
        for (int p = 0; p < PAR; ++p)
            act[p] = __shfl(act_mine, REPLANE(p), 64);

        #pragma unroll
        for (int p = 0; p < PAR; ++p) {
            const unsigned short* wo = WoT + (size_t)gidx[p] * DIM;
            const uint4 u0 = *(const uint4*)(wo + lane * 8);
            const uint4 u1 = *(const uint4*)(wo + 512 + lane * 8);
            const float a_ = act[p];
            half2v h_;
            h_ = as_h2(u0.x); acc[0]  = fmaf((float)h_.x, a_, acc[0]);  acc[1]  = fmaf((float)h_.y, a_, acc[1]);
            h_ = as_h2(u0.y); acc[2]  = fmaf((float)h_.x, a_, acc[2]);  acc[3]  = fmaf((float)h_.y, a_, acc[3]);
            h_ = as_h2(u0.z); acc[4]  = fmaf((float)h_.x, a_, acc[4]);  acc[5]  = fmaf((float)h_.y, a_, acc[5]);
            h_ = as_h2(u0.w); acc[6]  = fmaf((float)h_.x, a_, acc[6]);  acc[7]  = fmaf((float)h_.y, a_, acc[7]);
            h_ = as_h2(u1.x); acc[8]  = fmaf((float)h_.x, a_, acc[8]);  acc[9]  = fmaf((float)h_.y, a_, acc[9]);
            h_ = as_h2(u1.y); acc[10] = fmaf((float)h_.x, a_, acc[10]); acc[11] = fmaf((float)h_.y, a_, acc[11]);
            h_ = as_h2(u1.z); acc[12] = fmaf((float)h_.x, a_, acc[12]); acc[13] = fmaf((float)h_.y, a_, acc[13]);
            h_ = as_h2(u1.w); acc[14] = fmaf((float)h_.x, a_, acc[14]); acc[15] = fmaf((float)h_.y, a_, acc[15]);

            if (d < DEPTH) {
                const int np = (int)((nodes >> (8 * p)) & 0xffULL);
                const unsigned long long nn = (unsigned long long)
                    (2 * np + 1 + (int)((pos >> REPLANE(p)) & 1ULL));
                nodes = (nodes & ~(0xffULL << (8 * p))) | (nn << (8 * p));
            }
        }
    }

    float* orow = out + (size_t)wave * DIM;
    *(float4*)(orow + lane * 8 + 0)       = make_float4(acc[0],  acc[1],  acc[2],  acc[3]);
    *(float4*)(orow + lane * 8 + 4)       = make_float4(acc[4],  acc[5],  acc[6],  acc[7]);
    *(float4*)(orow + 512 + lane * 8 + 0) = make_float4(acc[8],  acc[9],  acc[10], acc[11]);
    *(float4*)(orow + 512 + lane * 8 + 4) = make_float4(acc[12], acc[13], acc[14], acc[15]);
}

// ---------------------------------------------------------------------------
// Fallback (no workspace): fp32 gather both stages. Correct but slow.
// ---------------------------------------------------------------------------
__global__ __launch_bounds__(256) void fff_fallback_kernel(
    const float* __restrict__ x, const float* __restrict__ W_in,
    const float* __restrict__ b_in, const float* __restrict__ W_out,
    float* __restrict__ out, int B)
{
    const int wave = (int)((blockIdx.x * blockDim.x + threadIdx.x) >> 6);
    const int lane = (int)(threadIdx.x & 63);
    if (wave >= B) return;

    const float* xr = x + (size_t)wave * DIM;
    float4 x4[4];
    x4[0] = *(const float4*)(xr + lane * 8 + 0);
    x4[1] = *(const float4*)(xr + lane * 8 + 4);
    x4[2] = *(const float4*)(xr + 512 + lane * 8 + 0);
    x4[3] = *(const float4*)(xr + 512 + lane * 8 + 4);

    float acc[16];
    #pragma unroll
    for (int i = 0; i < 16; ++i) acc[i] = 0.f;
    int node[PAR];
    #pragma unroll
    for (int p = 0; p < PAR; ++p) node[p] = 0;

    for (int d = 0; d <= DEPTH; ++d) {
        #pragma unroll
        for (int p = 0; p < PAR; ++p) {
            const int gidx = p * N_NODES + node[p];
            const float* wr = W_in + (size_t)gidx * DIM;
            const float4 wa = *(const float4*)(wr + lane * 8 + 0);
            const float4 wb = *(const float4*)(wr + lane * 8 + 4);
            const float4 wc = *(const float4*)(wr + 512 + lane * 8 + 0);
            const float4 wd = *(const float4*)(wr + 512 + lane * 8 + 4);
            float s = 0.f;
            s = fmaf(x4[0].x, wa.x, s); s = fmaf(x4[0].y, wa.y, s);
            s = fmaf(x4[0].z, wa.z, s); s = fmaf(x4[0].w, wa.w, s);
            s = fmaf(x4[1].x, wb.x, s); s = fmaf(x4[1].y, wb.y, s);
            s = fmaf(x4[1].z, wb.z, s); s = fmaf(x4[1].w, wb.w, s);
            s = fmaf(x4[2].x, wc.x, s); s = fmaf(x4[2].y, wc.y, s);
            s = fmaf(x4[2].z, wc.z, s); s = fmaf(x4[2].w, wc.w, s);
            s = fmaf(x4[3].x, wd.x, s); s = fmaf(x4[3].y, wd.y, s);
            s = fmaf(x4[3].z, wd.z, s); s = fmaf(x4[3].w, wd.w, s);
            #pragma unroll
            for (int off = 32; off >= 1; off >>= 1)
                s += __shfl_xor(s, off, 64);
            const float logit = s + b_in[gidx];
            const float act = logit / (1.0f + __expf(-logit));
            #pragma unroll
            for (int k = 0; k < 2; ++k) {
                #pragma unroll
                for (int j = 0; j < 8; ++j) {
                    const int e = k * 512 + lane * 8 + j;
                    acc[k * 8 + j] = fmaf(act, W_out[(size_t)e * WIDTH + gidx], acc[k * 8 + j]);
                }
            }
            node[p] = 2 * node[p] + 1 + ((logit > 0.0f) ? 1 : 0);
        }
    }

    float* orow = out + (size_t)wave * DIM;
    *(float4*)(orow + lane * 8 + 0)       = make_float4(acc[0],  acc[1],  acc[2],  acc[3]);
    *(float4*)(orow + lane * 8 + 4)       = make_float4(acc[4],  acc[5],  acc[6],  acc[7]);
    *(float4*)(orow + 512 + lane * 8 + 0) = make_float4(acc[8],  acc[9],  acc[10], acc[11]);
    *(float4*)(orow + 512 + lane * 8 + 4) = make_float4(acc[12], acc[13], acc[14], acc[15]);
}

extern "C" void kernel_launch(void* const* d_in, const int* in_sizes, int n_in,
                              void* d_out, int out_size, void* d_ws, size_t ws_size,
                              hipStream_t stream) {
    const float* oldx  = (const float*)d_in[0];
    const float* W_in  = (const float*)d_in[1];
    const float* b_in  = (const float*)d_in[2];
    const float* W_out = (const float*)d_in[3];
    float* out = (float*)d_out;

    const int B = in_sizes[0] / DIM;   // 8192 rows

    const size_t half   = (size_t)WIDTH * DIM * sizeof(unsigned short);  // 4.18 MB
    const size_t actsz  = (size_t)B * 64 * sizeof(float);                // 2 MB
    const size_t idxsz  = (size_t)B * 64 * sizeof(unsigned short);       // 1 MB
    const bool use_split = (d_ws != nullptr) && (ws_size >= 2 * half + actsz + idxsz);
    const bool use_lp    = (d_ws != nullptr) && (ws_size >= 2 * half);

    const int blocks = (B + 3) / 4;    // 4 waves (256 threads) per block

    if (use_split) {
        unsigned short* WoT  = (unsigned short*)d_ws;
        unsigned int*   Wh   = (unsigned int*)((char*)d_ws + half);
        float*          acts = (float*)((char*)d_ws + 2 * half);
        unsigned short* gidx = (unsigned short*)((char*)d_ws + 2 * half + actsz);
        prep_kernel<<<TRANS_BLOCKS + 1024, 256, 0, stream>>>(W_out, W_in, WoT, Wh);
        fff_stage1_kernel<<<blocks, 256, 0, stream>>>(oldx, W_in, b_in, Wh, acts, gidx, B);
        fff_stage2_kernel<<<blocks, 256, 0, stream>>>(acts, gidx, WoT, out, B);
    } else if (use_lp) {
        unsigned short* WoT = (unsigned short*)d_ws;
        unsigned int*   Wh  = (unsigned int*)((char*)d_ws + half);
        prep_kernel<<<TRANS_BLOCKS + 1024, 256, 0, stream>>>(W_out, W_in, WoT, Wh);
        fff_f16_kernel<<<blocks, 256, 0, stream>>>(oldx, W_in, b_in, Wh, WoT, out, B);
    } else {
        fff_fallback_kernel<<<blocks, 256, 0, stream>>>(oldx, W_in, b_in, W_out, out, B);
    }
}

// Round 6
// 179.103 us; speedup vs baseline: 2.8860x; 1.0113x over previous
//
#include <hip/hip_runtime.h>
#include <math.h>

#define DIM 1024
#define DEPTH 7
#define PAR 8
#define N_NODES 255   // 2^(DEPTH+1) - 1
#define WIDTH 2040    // PAR * N_NODES
// f16-dot error sigma ~3e-4; 0.01 is ~30 sigma.
#define MARGIN 0.01f

// lane that holds tree p's reduced logit after the fold network (bits 8/16/32)
#define REPLANE(p) ((((p) & 1) << 3) | ((((p) >> 1) & 1) << 4) | ((((p) >> 2) & 1) << 5))

typedef _Float16 half2v __attribute__((ext_vector_type(2)));

__device__ __forceinline__ half2v as_h2(unsigned int u) {
    union { unsigned int u; half2v h; } c; c.u = u; return c.h;
}
__device__ __forceinline__ unsigned int pack_h2(float a, float b) {
    union { half2v h; unsigned int u; } c;
    c.h = (half2v){(_Float16)a, (_Float16)b};   // v_cvt_f16_f32 is RTNE
    return c.u;
}

// f16 dot2 with fp32 accumulate; builtin if available, exact fallback otherwise
__device__ __forceinline__ float dot2h(unsigned int a, unsigned int b, float c) {
#if __has_builtin(__builtin_amdgcn_fdot2)
    return __builtin_amdgcn_fdot2(as_h2(a), as_h2(b), c, false);
#else
    half2v ha = as_h2(a), hb = as_h2(b);
    c = fmaf((float)ha.x, (float)hb.x, c);
    return fmaf((float)ha.y, (float)hb.y, c);
#endif
}

// fold two per-lane partial sums into one register, separating them by lane bit K.
__device__ __forceinline__ float foldK(float a, float b, int K) {
    const bool hi = (threadIdx.x & (unsigned)K) != 0;
    const float keep = hi ? b : a;
    const float send = hi ? a : b;
    return keep + __shfl_xor(send, K, 64);
}

// ---------------------------------------------------------------------------
// Fused prep: blocks [0,512) transpose+convert W_out f32 [DIM][WIDTH] ->
// WoT f16 [WIDTH][DIM]; blocks [512,...) convert W_in f32 -> f16 packed.
// ---------------------------------------------------------------------------
#define TRANS_BLOCKS 512   // 32 (WIDTH/64 tiles) x 16 (DIM/64 tiles)

__global__ __launch_bounds__(256) void prep_kernel(
    const float* __restrict__ W_out,      // [DIM][WIDTH] f32
    const float* __restrict__ W_in,       // [WIDTH][DIM] f32
    unsigned short* __restrict__ WoT,     // [WIDTH][DIM] f16
    unsigned int* __restrict__ Wh)        // [WIDTH][DIM/2] f16-pair dwords
{
    __shared__ float tile[64][65];
    if (blockIdx.x < TRANS_BLOCKS) {
        const int w0 = (int)(blockIdx.x & 31) * 64;
        const int d0 = (int)(blockIdx.x >> 5) * 64;
        const int tid = (int)threadIdx.x;
        const int sub = tid & 15;
        const int grp = tid >> 4;

        #pragma unroll
        for (int pass = 0; pass < 4; ++pass) {
            const int dl = pass * 16 + grp;
            const int wl = sub * 4;
            const int w = w0 + wl;
            const int d = d0 + dl;
            float4 v = make_float4(0.f, 0.f, 0.f, 0.f);
            if (w + 3 < WIDTH) {
                v = *(const float4*)(W_out + (size_t)d * WIDTH + w);
            } else {
                float t0 = (w + 0 < WIDTH) ? W_out[(size_t)d * WIDTH + w + 0] : 0.f;
                float t1 = (w + 1 < WIDTH) ? W_out[(size_t)d * WIDTH + w + 1] : 0.f;
                float t2 = (w + 2 < WIDTH) ? W_out[(size_t)d * WIDTH + w + 2] : 0.f;
                float t3 = (w + 3 < WIDTH) ? W_out[(size_t)d * WIDTH + w + 3] : 0.f;
                v = make_float4(t0, t1, t2, t3);
            }
            tile[dl][wl + 0] = v.x; tile[dl][wl + 1] = v.y;
            tile[dl][wl + 2] = v.z; tile[dl][wl + 3] = v.w;
        }
        __syncthreads();
        #pragma unroll
        for (int pass = 0; pass < 4; ++pass) {
            const int wl = pass * 16 + grp;
            const int dl = sub * 4;
            const int w = w0 + wl;
            if (w < WIDTH) {
                uint2 pk;
                pk.x = pack_h2(tile[dl + 0][wl], tile[dl + 1][wl]);
                pk.y = pack_h2(tile[dl + 2][wl], tile[dl + 3][wl]);
                *(uint2*)(WoT + (size_t)w * DIM + d0 + dl) = pk;
            }
        }
    } else {
        const int n4 = WIDTH * DIM / 4;
        const int nthr = ((int)gridDim.x - TRANS_BLOCKS) * 256;
        for (int i = ((int)blockIdx.x - TRANS_BLOCKS) * 256 + (int)threadIdx.x;
             i < n4; i += nthr) {
            float4 v = ((const float4*)W_in)[i];
            uint2 pk;
            pk.x = pack_h2(v.x, v.y);
            pk.y = pack_h2(v.z, v.w);
            ((uint2*)Wh)[i] = pk;
        }
    }
}

// ---------------------------------------------------------------------------
// Stage 1: traversal only, TWO rows per wave. The two traversals are
// independent instruction streams: row-B's loads+dots cover row-A's
// fold/ballot/repair latency and vice versa. Per-tree load loop is
// software-pipelined one tree ahead for both rows (4 uint4 live = 16 regs).
// Per row emits 64 (gidx u16, act f32) records (level-major, tree-minor).
// ---------------------------------------------------------------------------
__global__ __launch_bounds__(256) void fff_stage1_kernel(
    const float* __restrict__ x,            // [B, DIM] f32
    const float* __restrict__ W_in,         // [WIDTH, DIM] f32 (repair only)
    const float* __restrict__ b_in,         // [WIDTH] f32
    const unsigned int* __restrict__ Wh,    // f16 W_in [WIDTH][DIM/2] dwords
    float* __restrict__ acts,               // [B][64] f32
    unsigned short* __restrict__ gidx_out,  // [B][64] u16
    int B)
{
    const int wv = (int)((blockIdx.x * blockDim.x + threadIdx.x) >> 6);
    const int lane = (int)(threadIdx.x & 63);
    const int rowA = wv * 2;
    const int rowB = wv * 2 + 1;
    if (rowA >= B) return;
    const bool hasB = (rowB < B);

    const float* xrA = x + (size_t)rowA * DIM;
    const float* xrB = x + (size_t)(hasB ? rowB : rowA) * DIM;

    unsigned int xpA[8], xpB[8];
    {
        float4 a0 = *(const float4*)(xrA + lane * 8 + 0);
        float4 a1 = *(const float4*)(xrA + lane * 8 + 4);
        float4 a2 = *(const float4*)(xrA + 512 + lane * 8 + 0);
        float4 a3 = *(const float4*)(xrA + 512 + lane * 8 + 4);
        xpA[0] = pack_h2(a0.x, a0.y); xpA[1] = pack_h2(a0.z, a0.w);
        xpA[2] = pack_h2(a1.x, a1.y); xpA[3] = pack_h2(a1.z, a1.w);
        xpA[4] = pack_h2(a2.x, a2.y); xpA[5] = pack_h2(a2.z, a2.w);
        xpA[6] = pack_h2(a3.x, a3.y); xpA[7] = pack_h2(a3.z, a3.w);
        float4 b0 = *(const float4*)(xrB + lane * 8 + 0);
        float4 b1 = *(const float4*)(xrB + lane * 8 + 4);
        float4 b2 = *(const float4*)(xrB + 512 + lane * 8 + 0);
        float4 b3 = *(const float4*)(xrB + 512 + lane * 8 + 4);
        xpB[0] = pack_h2(b0.x, b0.y); xpB[1] = pack_h2(b0.z, b0.w);
        xpB[2] = pack_h2(b1.x, b1.y); xpB[3] = pack_h2(b1.z, b1.w);
        xpB[4] = pack_h2(b2.x, b2.y); xpB[5] = pack_h2(b2.z, b2.w);
        xpB[6] = pack_h2(b3.x, b3.y); xpB[7] = pack_h2(b3.z, b3.w);
    }

    unsigned long long nodesA = 0ULL, nodesB = 0ULL;   // 8 x u8 node indices
    const int myp = ((lane >> 3) & 1) | (((lane >> 4) & 1) << 1) | (((lane >> 5) & 1) << 2);

    #pragma unroll 1
    for (int d = 0; d <= DEPTH; ++d) {
        int gA[PAR], gB[PAR];
        #pragma unroll
        for (int p = 0; p < PAR; ++p) {
            gA[p] = p * N_NODES + (int)((nodesA >> (8 * p)) & 0xffULL);
            gB[p] = p * N_NODES + (int)((nodesB >> (8 * p)) & 0xffULL);
        }

        // per-lane owned node index (lane 8p owns tree p) + bias, both rows
        const int gaA = (lane & 8) ? gA[1] : gA[0];
        const int gbA = (lane & 8) ? gA[3] : gA[2];
        const int gcA = (lane & 8) ? gA[5] : gA[4];
        const int gdA = (lane & 8) ? gA[7] : gA[6];
        const int geA = (lane & 16) ? gbA : gaA;
        const int gfA = (lane & 16) ? gdA : gcA;
        const int gmineA = (lane & 32) ? gfA : geA;
        const float biasA = b_in[gmineA];
        const int gaB = (lane & 8) ? gB[1] : gB[0];
        const int gbB = (lane & 8) ? gB[3] : gB[2];
        const int gcB = (lane & 8) ? gB[5] : gB[4];
        const int gdB = (lane & 8) ? gB[7] : gB[6];
        const int geB = (lane & 16) ? gbB : gaB;
        const int gfB = (lane & 16) ? gdB : gcB;
        const int gmineB = (lane & 32) ? gfB : geB;
        const float biasB = b_in[gmineB];

        // Phase A: dual-row, pipelined one tree ahead (4 uint4 live)
        float pA[PAR], pB[PAR];
        uint4 a0, a1, b0, b1;
        {
            const unsigned int* wrA = Wh + (size_t)gA[0] * (DIM / 2);
            a0 = *(const uint4*)(wrA + lane * 4);
            a1 = *(const uint4*)(wrA + 256 + lane * 4);
            const unsigned int* wrB = Wh + (size_t)gB[0] * (DIM / 2);
            b0 = *(const uint4*)(wrB + lane * 4);
            b1 = *(const uint4*)(wrB + 256 + lane * 4);
        }
        #pragma unroll
        for (int p = 0; p < PAR; ++p) {
            uint4 na0 = a0, na1 = a1, nb0 = b0, nb1 = b1;
            if (p < PAR - 1) {
                const unsigned int* wrA = Wh + (size_t)gA[p + 1] * (DIM / 2);
                na0 = *(const uint4*)(wrA + lane * 4);
                na1 = *(const uint4*)(wrA + 256 + lane * 4);
                const unsigned int* wrB = Wh + (size_t)gB[p + 1] * (DIM / 2);
                nb0 = *(const uint4*)(wrB + lane * 4);
                nb1 = *(const uint4*)(wrB + 256 + lane * 4);
            }
            float s = 0.f;
            s = dot2h(xpA[0], a0.x, s);
            s = dot2h(xpA[1], a0.y, s);
            s = dot2h(xpA[2], a0.z, s);
            s = dot2h(xpA[3], a0.w, s);
            s = dot2h(xpA[4], a1.x, s);
            s = dot2h(xpA[5], a1.y, s);
            s = dot2h(xpA[6], a1.z, s);
            s = dot2h(xpA[7], a1.w, s);
            pA[p] = s;
            float t = 0.f;
            t = dot2h(xpB[0], b0.x, t);
            t = dot2h(xpB[1], b0.y, t);
            t = dot2h(xpB[2], b0.z, t);
            t = dot2h(xpB[3], b0.w, t);
            t = dot2h(xpB[4], b1.x, t);
            t = dot2h(xpB[5], b1.y, t);
            t = dot2h(xpB[6], b1.z, t);
            t = dot2h(xpB[7], b1.w, t);
            pB[p] = t;
            a0 = na0; a1 = na1; b0 = nb0; b1 = nb1;
        }

        // Phase B: two independent fold networks, interleaved at source so
        // their DS-latency chains overlap.
        const float cA01 = foldK(pA[0], pA[1], 8);
        const float cB01 = foldK(pB[0], pB[1], 8);
        const float cA23 = foldK(pA[2], pA[3], 8);
        const float cB23 = foldK(pB[2], pB[3], 8);
        const float cA45 = foldK(pA[4], pA[5], 8);
        const float cB45 = foldK(pB[4], pB[5], 8);
        const float cA67 = foldK(pA[6], pA[7], 8);
        const float cB67 = foldK(pB[6], pB[7], 8);
        const float dA0 = foldK(cA01, cA23, 16);
        const float dB0 = foldK(cB01, cB23, 16);
        const float dA1 = foldK(cA45, cA67, 16);
        const float dB1 = foldK(cB45, cB67, 16);
        float eA = foldK(dA0, dA1, 32);
        float eB = foldK(dB0, dB1, 32);
        eA += __shfl_xor(eA, 1, 64);  eB += __shfl_xor(eB, 1, 64);
        eA += __shfl_xor(eA, 2, 64);  eB += __shfl_xor(eB, 2, 64);
        eA += __shfl_xor(eA, 4, 64);  eB += __shfl_xor(eB, 4, 64);
        float myA = eA + biasA;
        float myB = eB + biasB;

        // Repair: near-zero logits recomputed in fp32 (decisions must match numpy)
        if (d < DEPTH) {
            const unsigned long long balA = __ballot(fabsf(myA) < MARGIN);
            unsigned rmA = 0;
            #pragma unroll
            for (int p = 0; p < PAR; ++p)
                rmA |= ((unsigned)((balA >> REPLANE(p)) & 1ULL)) << p;
            while (rmA) {
                const int p = __builtin_ctz(rmA); rmA &= (rmA - 1u);
                const int gi = p * N_NODES + (int)((nodesA >> (8 * p)) & 0xffULL);
                const float* wr = W_in + (size_t)gi * DIM;
                float s = 0.f;
                #pragma unroll
                for (int q = 0; q < 4; ++q) {
                    const int off = (q & 1) * 4 + (q >> 1) * 512 + lane * 8;
                    const float4 fx = *(const float4*)(xrA + off);
                    const float4 fw = *(const float4*)(wr + off);
                    s = fmaf(fx.x, fw.x, s); s = fmaf(fx.y, fw.y, s);
                    s = fmaf(fx.z, fw.z, s); s = fmaf(fx.w, fw.w, s);
                }
                #pragma unroll
                for (int off = 32; off >= 1; off >>= 1)
                    s += __shfl_xor(s, off, 64);
                const float lf = s + b_in[gi];
                myA = (myp == p) ? lf : myA;
            }
            const unsigned long long balB = __ballot(fabsf(myB) < MARGIN);
            unsigned rmB = 0;
            #pragma unroll
            for (int p = 0; p < PAR; ++p)
                rmB |= ((unsigned)((balB >> REPLANE(p)) & 1ULL)) << p;
            while (rmB) {
                const int p = __builtin_ctz(rmB); rmB &= (rmB - 1u);
                const int gi = p * N_NODES + (int)((nodesB >> (8 * p)) & 0xffULL);
                const float* wr = W_in + (size_t)gi * DIM;
                float s = 0.f;
                #pragma unroll
                for (int q = 0; q < 4; ++q) {
                    const int off = (q & 1) * 4 + (q >> 1) * 512 + lane * 8;
                    const float4 fx = *(const float4*)(xrB + off);
                    const float4 fw = *(const float4*)(wr + off);
                    s = fmaf(fx.x, fw.x, s); s = fmaf(fx.y, fw.y, s);
                    s = fmaf(fx.z, fw.z, s); s = fmaf(fx.w, fw.w, s);
                }
                #pragma unroll
                for (int off = 32; off >= 1; off >>= 1)
                    s += __shfl_xor(s, off, 64);
                const float lf = s + b_in[gi];
                myB = (myp == p) ? lf : myB;
            }
        }

        // per-lane silu; decisions via one ballot per row
        const float actA = myA / (1.0f + __expf(-myA));
        const float actB = myB / (1.0f + __expf(-myB));
        const unsigned long long posA = __ballot(myA > 0.0f);
        const unsigned long long posB = __ballot(myB > 0.0f);

        // lanes 0,8,...,56 own trees 0..7: emit (gidx, act) records
        if ((lane & 7) == 0) {
            const int slotA = (rowA << 6) + (d << 3) + myp;
            acts[slotA] = actA;
            gidx_out[slotA] = (unsigned short)gmineA;
            if (hasB) {
                const int slotB = (rowB << 6) + (d << 3) + myp;
                acts[slotB] = actB;
                gidx_out[slotB] = (unsigned short)gmineB;
            }
        }

        if (d < DEPTH) {
            #pragma unroll
            for (int p = 0; p < PAR; ++p) {
                const int npA = (int)((nodesA >> (8 * p)) & 0xffULL);
                const unsigned long long nnA = (unsigned long long)
                    (2 * npA + 1 + (int)((posA >> REPLANE(p)) & 1ULL));
                nodesA = (nodesA & ~(0xffULL << (8 * p))) | (nnA << (8 * p));
                const int npB = (int)((nodesB >> (8 * p)) & 0xffULL);
                const unsigned long long nnB = (unsigned long long)
                    (2 * npB + 1 + (int)((posB >> REPLANE(p)) & 1ULL));
                nodesB = (nodesB & ~(0xffULL << (8 * p))) | (nnB << (8 * p));
            }
        }
    }
}

// ---------------------------------------------------------------------------
// Stage 2: gather-axpy. One wave per row; 64 (act, gidx) axpy iterations.
// (Unchanged from r5 -- kept identical so its counters surface cleanly.)
// ---------------------------------------------------------------------------
__global__ __launch_bounds__(256) void fff_stage2_kernel(
    const float* __restrict__ acts,          // [B][64] f32
    const unsigned short* __restrict__ gidx16, // [B][64] u16
    const unsigned short* __restrict__ WoT,  // f16 W_out^T [WIDTH][DIM]
    float* __restrict__ out,                 // [B, DIM] f32
    int B)
{
    const int wave = (int)((blockIdx.x * blockDim.x + threadIdx.x) >> 6);
    const int lane = (int)(threadIdx.x & 63);
    if (wave >= B) return;

    const int base = wave << 6;
    const float a_l = acts[base + lane];         // lane e holds record e
    const int   g_l = (int)gidx16[base + lane];

    float acc[16];
    #pragma unroll
    for (int i = 0; i < 16; ++i) acc[i] = 0.f;

    #pragma unroll 4
    for (int e = 0; e < 64; ++e) {
        const float a_ = __shfl(a_l, e, 64);
        const int   g  = __shfl(g_l, e, 64);
        const unsigned short* wo = WoT + (size_t)g * DIM;
        const uint4 u0 = *(const uint4*)(wo + lane * 8);
        const uint4 u1 = *(const uint4*)(wo + 512 + lane * 8);
        half2v h_;
        h_ = as_h2(u0.x); acc[0]  = fmaf((float)h_.x, a_, acc[0]);  acc[1]  = fmaf((float)h_.y, a_, acc[1]);
        h_ = as_h2(u0.y); acc[2]  = fmaf((float)h_.x, a_, acc[2]);  acc[3]  = fmaf((float)h_.y, a_, acc[3]);
        h_ = as_h2(u0.z); acc[4]  = fmaf((float)h_.x, a_, acc[4]);  acc[5]  = fmaf((float)h_.y, a_, acc[5]);
        h_ = as_h2(u0.w); acc[6]  = fmaf((float)h_.x, a_, acc[6]);  acc[7]  = fmaf((float)h_.y, a_, acc[7]);
        h_ = as_h2(u1.x); acc[8]  = fmaf((float)h_.x, a_, acc[8]);  acc[9]  = fmaf((float)h_.y, a_, acc[9]);
        h_ = as_h2(u1.y); acc[10] = fmaf((float)h_.x, a_, acc[10]); acc[11] = fmaf((float)h_.y, a_, acc[11]);
        h_ = as_h2(u1.z); acc[12] = fmaf((float)h_.x, a_, acc[12]); acc[13] = fmaf((float)h_.y, a_, acc[13]);
        h_ = as_h2(u1.w); acc[14] = fmaf((float)h_.x, a_, acc[14]); acc[15] = fmaf((float)h_.y, a_, acc[15]);
    }

    float* orow = out + (size_t)wave * DIM;
    *(float4*)(orow + lane * 8 + 0)       = make_float4(acc[0],  acc[1],  acc[2],  acc[3]);
    *(float4*)(orow + lane * 8 + 4)       = make_float4(acc[4],  acc[5],  acc[6],  acc[7]);
    *(float4*)(orow + 512 + lane * 8 + 0) = make_float4(acc[8],  acc[9],  acc[10], acc[11]);
    *(float4*)(orow + 512 + lane * 8 + 4) = make_float4(acc[12], acc[13], acc[14], acc[15]);
}

// ---------------------------------------------------------------------------
// Fused single-kernel path (verified r4 version) -- used if workspace is too
// small for the split intermediates but fits the f16 weight tables.
// ---------------------------------------------------------------------------
__global__ __launch_bounds__(256) void fff_f16_kernel(
    const float* __restrict__ x,
    const float* __restrict__ W_in,
    const float* __restrict__ b_in,
    const unsigned int* __restrict__ Wh,
    const unsigned short* __restrict__ WoT,
    float* __restrict__ out,
    int B)
{
    const int wave = (int)((blockIdx.x * blockDim.x + threadIdx.x) >> 6);
    const int lane = (int)(threadIdx.x & 63);
    if (wave >= B) return;

    const float* xr = x + (size_t)wave * DIM;
    unsigned int xp[8];
    {
        float4 a0 = *(const float4*)(xr + lane * 8 + 0);
        float4 a1 = *(const float4*)(xr + lane * 8 + 4);
        float4 a2 = *(const float4*)(xr + 512 + lane * 8 + 0);
        float4 a3 = *(const float4*)(xr + 512 + lane * 8 + 4);
        xp[0] = pack_h2(a0.x, a0.y);
        xp[1] = pack_h2(a0.z, a0.w);
        xp[2] = pack_h2(a1.x, a1.y);
        xp[3] = pack_h2(a1.z, a1.w);
        xp[4] = pack_h2(a2.x, a2.y);
        xp[5] = pack_h2(a2.z, a2.w);
        xp[6] = pack_h2(a3.x, a3.y);
        xp[7] = pack_h2(a3.z, a3.w);
    }

    float acc[16];
    #pragma unroll
    for (int i = 0; i < 16; ++i) acc[i] = 0.f;

    unsigned long long nodes = 0ULL;
    const int myp = ((lane >> 3) & 1) | (((lane >> 4) & 1) << 1) | (((lane >> 5) & 1) << 2);

    #pragma unroll 1
    for (int d = 0; d <= DEPTH; ++d) {
        int gidx[PAR];
        #pragma unroll
        for (int p = 0; p < PAR; ++p) {
            const int np = (int)((nodes >> (8 * p)) & 0xffULL);
            gidx[p] = p * N_NODES + np;
        }

        const int ga = (lane & 8) ? gidx[1] : gidx[0];
        const int gb = (lane & 8) ? gidx[3] : gidx[2];
        const int gc = (lane & 8) ? gidx[5] : gidx[4];
        const int gd = (lane & 8) ? gidx[7] : gidx[6];
        const int ge = (lane & 16) ? gb : ga;
        const int gf = (lane & 16) ? gd : gc;
        const int gmine = (lane & 32) ? gf : ge;
        const float bias = b_in[gmine];

        float partial[PAR];
        #pragma unroll
        for (int p = 0; p < PAR; ++p) {
            const unsigned int* wr = Wh + (size_t)gidx[p] * (DIM / 2);
            const uint4 u0 = *(const uint4*)(wr + lane * 4);
            const uint4 u1 = *(const uint4*)(wr + 256 + lane * 4);
            float s = 0.f;
            s = dot2h(xp[0], u0.x, s);
            s = dot2h(xp[1], u0.y, s);
            s = dot2h(xp[2], u0.z, s);
            s = dot2h(xp[3], u0.w, s);
            s = dot2h(xp[4], u1.x, s);
            s = dot2h(xp[5], u1.y, s);
            s = dot2h(xp[6], u1.z, s);
            s = dot2h(xp[7], u1.w, s);
            partial[p] = s;
        }

        const float c01 = foldK(partial[0], partial[1], 8);
        const float c23 = foldK(partial[2], partial[3], 8);
        const float c45 = foldK(partial[4], partial[5], 8);
        const float c67 = foldK(partial[6], partial[7], 8);
        const float d0f = foldK(c01, c23, 16);
        const float d1f = foldK(c45, c67, 16);
        float e = foldK(d0f, d1f, 32);
        e += __shfl_xor(e, 1, 64);
        e += __shfl_xor(e, 2, 64);
        e += __shfl_xor(e, 4, 64);
        float my = e + bias;

        if (d < DEPTH) {
            const unsigned long long bal = __ballot(fabsf(my) < MARGIN);
            unsigned rm = 0;
            #pragma unroll
            for (int p = 0; p < PAR; ++p)
                rm |= ((unsigned)((bal >> REPLANE(p)) & 1ULL)) << p;
            if (rm) {
                while (rm) {
                    const int p = __builtin_ctz(rm); rm &= (rm - 1u);
                    const int np = (int)((nodes >> (8 * p)) & 0xffULL);
                    const int gi = p * N_NODES + np;
                    const float* wr = W_in + (size_t)gi * DIM;
                    float s = 0.f;
                    #pragma unroll
                    for (int q = 0; q < 4; ++q) {
                        const int off = (q & 1) * 4 + (q >> 1) * 512 + lane * 8;
                        const float4 fx = *(const float4*)(xr + off);
                        const float4 fw = *(const float4*)(wr + off);
                        s = fmaf(fx.x, fw.x, s); s = fmaf(fx.y, fw.y, s);
                        s = fmaf(fx.z, fw.z, s); s = fmaf(fx.w, fw.w, s);
                    }
                    #pragma unroll
                    for (int off = 32; off >= 1; off >>= 1)
                        s += __shfl_xor(s, off, 64);
                    const float lf = s + b_in[gi];
                    my = (myp == p) ? lf : my;
                }
            }
        }

        const float act_mine = my / (1.0f + __expf(-my));
        const unsigned long long pos = __ballot(my > 0.0f);

        float act[PAR];
        #pragma unroll
        for (int p = 0; p < PAR; ++p)
            act[p] = __shfl(act_mine, REPLANE(p), 64);

        #pragma unroll
        for (int p = 0; p < PAR; ++p) {
            const unsigned short* wo = WoT + (size_t)gidx[p] * DIM;
            const uint4 u0 = *(const uint4*)(wo + lane * 8);
            const uint4 u1 = *(const uint4*)(wo + 512 + lane * 8);
            const float a_ = act[p];
            half2v h_;
            h_ = as_h2(u0.x); acc[0]  = fmaf((float)h_.x, a_, acc[0]);  acc[1]  = fmaf((float)h_.y, a_, acc[1]);
            h_ = as_h2(u0.y); acc[2]  = fmaf((float)h_.x, a_, acc[2]);  acc[3]  = fmaf((float)h_.y, a_, acc[3]);
            h_ = as_h2(u0.z); acc[4]  = fmaf((float)h_.x, a_, acc[4]);  acc[5]  = fmaf((float)h_.y, a_, acc[5]);
            h_ = as_h2(u0.w); acc[6]  = fmaf((float)h_.x, a_, acc[6]);  acc[7]  = fmaf((float)h_.y, a_, acc[7]);
            h_ = as_h2(u1.x); acc[8]  = fmaf((float)h_.x, a_, acc[8]);  acc[9]  = fmaf((float)h_.y, a_, acc[9]);
            h_ = as_h2(u1.y); acc[10] = fmaf((float)h_.x, a_, acc[10]); acc[11] = fmaf((float)h_.y, a_, acc[11]);
            h_ = as_h2(u1.z); acc[12] = fmaf((float)h_.x, a_, acc[12]); acc[13] = fmaf((float)h_.y, a_, acc[13]);
            h_ = as_h2(u1.w); acc[14] = fmaf((float)h_.x, a_, acc[14]); acc[15] = fmaf((float)h_.y, a_, acc[15]);

            if (d < DEPTH) {
                const int np = (int)((nodes >> (8 * p)) & 0xffULL);
                const unsigned long long nn = (unsigned long long)
                    (2 * np + 1 + (int)((pos >> REPLANE(p)) & 1ULL));
                nodes = (nodes & ~(0xffULL << (8 * p))) | (nn << (8 * p));
            }
        }
    }

    float* orow = out + (size_t)wave * DIM;
    *(float4*)(orow + lane * 8 + 0)       = make_float4(acc[0],  acc[1],  acc[2],  acc[3]);
    *(float4*)(orow + lane * 8 + 4)       = make_float4(acc[4],  acc[5],  acc[6],  acc[7]);
    *(float4*)(orow + 512 + lane * 8 + 0) = make_float4(acc[8],  acc[9],  acc[10], acc[11]);
    *(float4*)(orow + 512 + lane * 8 + 4) = make_float4(acc[12], acc[13], acc[14], acc[15]);
}

// ---------------------------------------------------------------------------
// Fallback (no workspace): fp32 gather both stages. Correct but slow.
// ---------------------------------------------------------------------------
__global__ __launch_bounds__(256) void fff_fallback_kernel(
    const float* __restrict__ x, const float* __restrict__ W_in,
    const float* __restrict__ b_in, const float* __restrict__ W_out,
    float* __restrict__ out, int B)
{
    const int wave = (int)((blockIdx.x * blockDim.x + threadIdx.x) >> 6);
    const int lane = (int)(threadIdx.x & 63);
    if (wave >= B) return;

    const float* xr = x + (size_t)wave * DIM;
    float4 x4[4];
    x4[0] = *(const float4*)(xr + lane * 8 + 0);
    x4[1] = *(const float4*)(xr + lane * 8 + 4);
    x4[2] = *(const float4*)(xr + 512 + lane * 8 + 0);
    x4[3] = *(const float4*)(xr + 512 + lane * 8 + 4);

    float acc[16];
    #pragma unroll
    for (int i = 0; i < 16; ++i) acc[i] = 0.f;
    int node[PAR];
    #pragma unroll
    for (int p = 0; p < PAR; ++p) node[p] = 0;

    for (int d = 0; d <= DEPTH; ++d) {
        #pragma unroll
        for (int p = 0; p < PAR; ++p) {
            const int gidx = p * N_NODES + node[p];
            const float* wr = W_in + (size_t)gidx * DIM;
            const float4 wa = *(const float4*)(wr + lane * 8 + 0);
            const float4 wb = *(const float4*)(wr + lane * 8 + 4);
            const float4 wc = *(const float4*)(wr + 512 + lane * 8 + 0);
            const float4 wd = *(const float4*)(wr + 512 + lane * 8 + 4);
            float s = 0.f;
            s = fmaf(x4[0].x, wa.x, s); s = fmaf(x4[0].y, wa.y, s);
            s = fmaf(x4[0].z, wa.z, s); s = fmaf(x4[0].w, wa.w, s);
            s = fmaf(x4[1].x, wb.x, s); s = fmaf(x4[1].y, wb.y, s);
            s = fmaf(x4[1].z, wb.z, s); s = fmaf(x4[1].w, wb.w, s);
            s = fmaf(x4[2].x, wc.x, s); s = fmaf(x4[2].y, wc.y, s);
            s = fmaf(x4[2].z, wc.z, s); s = fmaf(x4[2].w, wc.w, s);
            s = fmaf(x4[3].x, wd.x, s); s = fmaf(x4[3].y, wd.y, s);
            s = fmaf(x4[3].z, wd.z, s); s = fmaf(x4[3].w, wd.w, s);
            #pragma unroll
            for (int off = 32; off >= 1; off >>= 1)
                s += __shfl_xor(s, off, 64);
            const float logit = s + b_in[gidx];
            const float act = logit / (1.0f + __expf(-logit));
            #pragma unroll
            for (int k = 0; k < 2; ++k) {
                #pragma unroll
                for (int j = 0; j < 8; ++j) {
                    const int e = k * 512 + lane * 8 + j;
                    acc[k * 8 + j] = fmaf(act, W_out[(size_t)e * WIDTH + gidx], acc[k * 8 + j]);
                }
            }
            node[p] = 2 * node[p] + 1 + ((logit > 0.0f) ? 1 : 0);
        }
    }

    float* orow = out + (size_t)wave * DIM;
    *(float4*)(orow + lane * 8 + 0)       = make_float4(acc[0],  acc[1],  acc[2],  acc[3]);
    *(float4*)(orow + lane * 8 + 4)       = make_float4(acc[4],  acc[5],  acc[6],  acc[7]);
    *(float4*)(orow + 512 + lane * 8 + 0) = make_float4(acc[8],  acc[9],  acc[10], acc[11]);
    *(float4*)(orow + 512 + lane * 8 + 4) = make_float4(acc[12], acc[13], acc[14], acc[15]);
}

extern "C" void kernel_launch(void* const* d_in, const int* in_sizes, int n_in,
                              void* d_out, int out_size, void* d_ws, size_t ws_size,
                              hipStream_t stream) {
    const float* oldx  = (const float*)d_in[0];
    const float* W_in  = (const float*)d_in[1];
    const float* b_in  = (const float*)d_in[2];
    const float* W_out = (const float*)d_in[3];
    float* out = (float*)d_out;

    const int B = in_sizes[0] / DIM;   // 8192 rows

    const size_t half   = (size_t)WIDTH * DIM * sizeof(unsigned short);  // 4.18 MB
    const size_t actsz  = (size_t)B * 64 * sizeof(float);                // 2 MB
    const size_t idxsz  = (size_t)B * 64 * sizeof(unsigned short);       // 1 MB
    const bool use_split = (d_ws != nullptr) && (ws_size >= 2 * half + actsz + idxsz);
    const bool use_lp    = (d_ws != nullptr) && (ws_size >= 2 * half);

    const int blocks = (B + 3) / 4;    // 4 waves (256 threads) per block

    if (use_split) {
        unsigned short* WoT  = (unsigned short*)d_ws;
        unsigned int*   Wh   = (unsigned int*)((char*)d_ws + half);
        float*          acts = (float*)((char*)d_ws + 2 * half);
        unsigned short* gidx = (unsigned short*)((char*)d_ws + 2 * half + actsz);
        prep_kernel<<<TRANS_BLOCKS + 1024, 256, 0, stream>>>(W_out, W_in, WoT, Wh);
        const int wavesS1 = (B + 1) / 2;              // two rows per wave
        const int blocksS1 = (wavesS1 + 3) / 4;
        fff_stage1_kernel<<<blocksS1, 256, 0, stream>>>(oldx, W_in, b_in, Wh, acts, gidx, B);
        fff_stage2_kernel<<<blocks, 256, 0, stream>>>(acts, gidx, WoT, out, B);
    } else if (use_lp) {
        unsigned short* WoT = (unsigned short*)d_ws;
        unsigned int*   Wh  = (unsigned int*)((char*)d_ws + half);
        prep_kernel<<<TRANS_BLOCKS + 1024, 256, 0, stream>>>(W_out, W_in, WoT, Wh);
        fff_f16_kernel<<<blocks, 256, 0, stream>>>(oldx, W_in, b_in, Wh, WoT, out, B);
    } else {
        fff_fallback_kernel<<<blocks, 256, 0, stream>>>(oldx, W_in, b_in, W_out, out, B);
    }
}

// Round 7
// 176.311 us; speedup vs baseline: 2.9317x; 1.0158x over previous
//
#include <hip/hip_runtime.h>
#include <math.h>

#define DIM 1024
#define DEPTH 7
#define PAR 8
#define N_NODES 255   // 2^(DEPTH+1) - 1
#define WIDTH 2040    // PAR * N_NODES
// f16-dot error sigma ~3e-4; 0.01 is ~30 sigma.
#define MARGIN 0.01f

// lane that holds tree p's reduced logit after the fold network (bits 8/16/32)
#define REPLANE(p) ((((p) & 1) << 3) | ((((p) >> 1) & 1) << 4) | ((((p) >> 2) & 1) << 5))

typedef _Float16 half2v __attribute__((ext_vector_type(2)));

__device__ __forceinline__ half2v as_h2(unsigned int u) {
    union { unsigned int u; half2v h; } c; c.u = u; return c.h;
}
__device__ __forceinline__ unsigned int pack_h2(float a, float b) {
    union { half2v h; unsigned int u; } c;
    c.h = (half2v){(_Float16)a, (_Float16)b};   // v_cvt_f16_f32 is RTNE
    return c.u;
}

// f16 dot2 with fp32 accumulate; builtin if available, exact fallback otherwise
__device__ __forceinline__ float dot2h(unsigned int a, unsigned int b, float c) {
#if __has_builtin(__builtin_amdgcn_fdot2)
    return __builtin_amdgcn_fdot2(as_h2(a), as_h2(b), c, false);
#else
    half2v ha = as_h2(a), hb = as_h2(b);
    c = fmaf((float)ha.x, (float)hb.x, c);
    return fmaf((float)ha.y, (float)hb.y, c);
#endif
}

// fold two per-lane partial sums into one register, separating them by lane bit K.
__device__ __forceinline__ float foldK(float a, float b, int K) {
    const bool hi = (threadIdx.x & (unsigned)K) != 0;
    const float keep = hi ? b : a;
    const float send = hi ? a : b;
    return keep + __shfl_xor(send, K, 64);
}

// ---------------------------------------------------------------------------
// Fused prep: blocks [0,512) transpose+convert W_out f32 [DIM][WIDTH] ->
// WoT f16 [WIDTH][DIM]; blocks [512,...) convert W_in f32 -> f16 packed.
// ---------------------------------------------------------------------------
#define TRANS_BLOCKS 512   // 32 (WIDTH/64 tiles) x 16 (DIM/64 tiles)

__global__ __launch_bounds__(256) void prep_kernel(
    const float* __restrict__ W_out,      // [DIM][WIDTH] f32
    const float* __restrict__ W_in,       // [WIDTH][DIM] f32
    unsigned short* __restrict__ WoT,     // [WIDTH][DIM] f16
    unsigned int* __restrict__ Wh)        // [WIDTH][DIM/2] f16-pair dwords
{
    __shared__ float tile[64][65];
    if (blockIdx.x < TRANS_BLOCKS) {
        const int w0 = (int)(blockIdx.x & 31) * 64;
        const int d0 = (int)(blockIdx.x >> 5) * 64;
        const int tid = (int)threadIdx.x;
        const int sub = tid & 15;
        const int grp = tid >> 4;

        #pragma unroll
        for (int pass = 0; pass < 4; ++pass) {
            const int dl = pass * 16 + grp;
            const int wl = sub * 4;
            const int w = w0 + wl;
            const int d = d0 + dl;
            float4 v = make_float4(0.f, 0.f, 0.f, 0.f);
            if (w + 3 < WIDTH) {
                v = *(const float4*)(W_out + (size_t)d * WIDTH + w);
            } else {
                float t0 = (w + 0 < WIDTH) ? W_out[(size_t)d * WIDTH + w + 0] : 0.f;
                float t1 = (w + 1 < WIDTH) ? W_out[(size_t)d * WIDTH + w + 1] : 0.f;
                float t2 = (w + 2 < WIDTH) ? W_out[(size_t)d * WIDTH + w + 2] : 0.f;
                float t3 = (w + 3 < WIDTH) ? W_out[(size_t)d * WIDTH + w + 3] : 0.f;
                v = make_float4(t0, t1, t2, t3);
            }
            tile[dl][wl + 0] = v.x; tile[dl][wl + 1] = v.y;
            tile[dl][wl + 2] = v.z; tile[dl][wl + 3] = v.w;
        }
        __syncthreads();
        #pragma unroll
        for (int pass = 0; pass < 4; ++pass) {
            const int wl = pass * 16 + grp;
            const int dl = sub * 4;
            const int w = w0 + wl;
            if (w < WIDTH) {
                uint2 pk;
                pk.x = pack_h2(tile[dl + 0][wl], tile[dl + 1][wl]);
                pk.y = pack_h2(tile[dl + 2][wl], tile[dl + 3][wl]);
                *(uint2*)(WoT + (size_t)w * DIM + d0 + dl) = pk;
            }
        }
    } else {
        const int n4 = WIDTH * DIM / 4;
        const int nthr = ((int)gridDim.x - TRANS_BLOCKS) * 256;
        for (int i = ((int)blockIdx.x - TRANS_BLOCKS) * 256 + (int)threadIdx.x;
             i < n4; i += nthr) {
            float4 v = ((const float4*)W_in)[i];
            uint2 pk;
            pk.x = pack_h2(v.x, v.y);
            pk.y = pack_h2(v.z, v.w);
            ((uint2*)Wh)[i] = pk;
        }
    }
}

// ---------------------------------------------------------------------------
// Fused dual-row kernel: TWO rows per wave, traversal + axpy in one pass.
// At this grid (B/2 waves = 16 waves/CU) occupancy is grid-capped at
// 4 waves/SIMD, so VGPRs up to 128 are free -- spent on two independent
// instruction streams (row A / row B) whose loads fill each other's
// fold-network and phase-C latency bubbles. act broadcast is done
// just-in-time and gidx is rematerialized from `nodes` in phase C to keep
// peak pressure under the 128 tier.
// ---------------------------------------------------------------------------
__global__ __launch_bounds__(256) void fff_fused2_kernel(
    const float* __restrict__ x,            // [B, DIM] f32
    const float* __restrict__ W_in,         // [WIDTH, DIM] f32 (repair only)
    const float* __restrict__ b_in,         // [WIDTH] f32
    const unsigned int* __restrict__ Wh,    // f16 W_in [WIDTH][DIM/2] dwords
    const unsigned short* __restrict__ WoT, // f16 W_out^T [WIDTH][DIM]
    float* __restrict__ out,                // [B, DIM] f32
    int B)
{
    const int wv = (int)((blockIdx.x * blockDim.x + threadIdx.x) >> 6);
    const int lane = (int)(threadIdx.x & 63);
    const int rowA = wv * 2;
    const int rowB = wv * 2 + 1;
    if (rowA >= B) return;
    const bool hasB = (rowB < B);

    const float* xrA = x + (size_t)rowA * DIM;
    const float* xrB = x + (size_t)(hasB ? rowB : rowA) * DIM;

    unsigned int xpA[8], xpB[8];
    {
        float4 a0 = *(const float4*)(xrA + lane * 8 + 0);
        float4 a1 = *(const float4*)(xrA + lane * 8 + 4);
        float4 a2 = *(const float4*)(xrA + 512 + lane * 8 + 0);
        float4 a3 = *(const float4*)(xrA + 512 + lane * 8 + 4);
        xpA[0] = pack_h2(a0.x, a0.y); xpA[1] = pack_h2(a0.z, a0.w);
        xpA[2] = pack_h2(a1.x, a1.y); xpA[3] = pack_h2(a1.z, a1.w);
        xpA[4] = pack_h2(a2.x, a2.y); xpA[5] = pack_h2(a2.z, a2.w);
        xpA[6] = pack_h2(a3.x, a3.y); xpA[7] = pack_h2(a3.z, a3.w);
        float4 b0 = *(const float4*)(xrB + lane * 8 + 0);
        float4 b1 = *(const float4*)(xrB + lane * 8 + 4);
        float4 b2 = *(const float4*)(xrB + 512 + lane * 8 + 0);
        float4 b3 = *(const float4*)(xrB + 512 + lane * 8 + 4);
        xpB[0] = pack_h2(b0.x, b0.y); xpB[1] = pack_h2(b0.z, b0.w);
        xpB[2] = pack_h2(b1.x, b1.y); xpB[3] = pack_h2(b1.z, b1.w);
        xpB[4] = pack_h2(b2.x, b2.y); xpB[5] = pack_h2(b2.z, b2.w);
        xpB[6] = pack_h2(b3.x, b3.y); xpB[7] = pack_h2(b3.z, b3.w);
    }

    float accA[16], accB[16];
    #pragma unroll
    for (int i = 0; i < 16; ++i) { accA[i] = 0.f; accB[i] = 0.f; }

    unsigned long long nodesA = 0ULL, nodesB = 0ULL;   // 8 x u8 node indices
    const int myp = ((lane >> 3) & 1) | (((lane >> 4) & 1) << 1) | (((lane >> 5) & 1) << 2);

    #pragma unroll 1
    for (int d = 0; d <= DEPTH; ++d) {
        int gA[PAR], gB[PAR];
        #pragma unroll
        for (int p = 0; p < PAR; ++p) {
            gA[p] = p * N_NODES + (int)((nodesA >> (8 * p)) & 0xffULL);
            gB[p] = p * N_NODES + (int)((nodesB >> (8 * p)) & 0xffULL);
        }

        // per-lane owned node index (lane 8p owns tree p) + bias, both rows
        const int gaA = (lane & 8) ? gA[1] : gA[0];
        const int gbA = (lane & 8) ? gA[3] : gA[2];
        const int gcA = (lane & 8) ? gA[5] : gA[4];
        const int gdA = (lane & 8) ? gA[7] : gA[6];
        const int geA = (lane & 16) ? gbA : gaA;
        const int gfA = (lane & 16) ? gdA : gcA;
        const int gmineA = (lane & 32) ? gfA : geA;
        const float biasA = b_in[gmineA];
        const int gaB = (lane & 8) ? gB[1] : gB[0];
        const int gbB = (lane & 8) ? gB[3] : gB[2];
        const int gcB = (lane & 8) ? gB[5] : gB[4];
        const int gdB = (lane & 8) ? gB[7] : gB[6];
        const int geB = (lane & 16) ? gbB : gaB;
        const int gfB = (lane & 16) ? gdB : gcB;
        const int gmineB = (lane & 32) ? gfB : geB;
        const float biasB = b_in[gmineB];

        // Phase A: dual-row dots, pipelined one tree ahead (4 uint4 live)
        float pA[PAR], pB[PAR];
        uint4 a0, a1, b0, b1;
        {
            const unsigned int* wrA = Wh + (size_t)gA[0] * (DIM / 2);
            a0 = *(const uint4*)(wrA + lane * 4);
            a1 = *(const uint4*)(wrA + 256 + lane * 4);
            const unsigned int* wrB = Wh + (size_t)gB[0] * (DIM / 2);
            b0 = *(const uint4*)(wrB + lane * 4);
            b1 = *(const uint4*)(wrB + 256 + lane * 4);
        }
        #pragma unroll
        for (int p = 0; p < PAR; ++p) {
            uint4 na0 = a0, na1 = a1, nb0 = b0, nb1 = b1;
            if (p < PAR - 1) {
                const unsigned int* wrA = Wh + (size_t)gA[p + 1] * (DIM / 2);
                na0 = *(const uint4*)(wrA + lane * 4);
                na1 = *(const uint4*)(wrA + 256 + lane * 4);
                const unsigned int* wrB = Wh + (size_t)gB[p + 1] * (DIM / 2);
                nb0 = *(const uint4*)(wrB + lane * 4);
                nb1 = *(const uint4*)(wrB + 256 + lane * 4);
            }
            float s = 0.f;
            s = dot2h(xpA[0], a0.x, s);
            s = dot2h(xpA[1], a0.y, s);
            s = dot2h(xpA[2], a0.z, s);
            s = dot2h(xpA[3], a0.w, s);
            s = dot2h(xpA[4], a1.x, s);
            s = dot2h(xpA[5], a1.y, s);
            s = dot2h(xpA[6], a1.z, s);
            s = dot2h(xpA[7], a1.w, s);
            pA[p] = s;
            float t = 0.f;
            t = dot2h(xpB[0], b0.x, t);
            t = dot2h(xpB[1], b0.y, t);
            t = dot2h(xpB[2], b0.z, t);
            t = dot2h(xpB[3], b0.w, t);
            t = dot2h(xpB[4], b1.x, t);
            t = dot2h(xpB[5], b1.y, t);
            t = dot2h(xpB[6], b1.z, t);
            t = dot2h(xpB[7], b1.w, t);
            pB[p] = t;
            a0 = na0; a1 = na1; b0 = nb0; b1 = nb1;
        }

        // Phase B: two independent fold networks, interleaved
        const float cA01 = foldK(pA[0], pA[1], 8);
        const float cB01 = foldK(pB[0], pB[1], 8);
        const float cA23 = foldK(pA[2], pA[3], 8);
        const float cB23 = foldK(pB[2], pB[3], 8);
        const float cA45 = foldK(pA[4], pA[5], 8);
        const float cB45 = foldK(pB[4], pB[5], 8);
        const float cA67 = foldK(pA[6], pA[7], 8);
        const float cB67 = foldK(pB[6], pB[7], 8);
        const float dA0 = foldK(cA01, cA23, 16);
        const float dB0 = foldK(cB01, cB23, 16);
        const float dA1 = foldK(cA45, cA67, 16);
        const float dB1 = foldK(cB45, cB67, 16);
        float eA = foldK(dA0, dA1, 32);
        float eB = foldK(dB0, dB1, 32);
        eA += __shfl_xor(eA, 1, 64);  eB += __shfl_xor(eB, 1, 64);
        eA += __shfl_xor(eA, 2, 64);  eB += __shfl_xor(eB, 2, 64);
        eA += __shfl_xor(eA, 4, 64);  eB += __shfl_xor(eB, 4, 64);
        float myA = eA + biasA;
        float myB = eB + biasB;

        // Repair: near-zero logits recomputed in fp32 (decisions must match numpy)
        if (d < DEPTH) {
            const unsigned long long balA = __ballot(fabsf(myA) < MARGIN);
            unsigned rmA = 0;
            #pragma unroll
            for (int p = 0; p < PAR; ++p)
                rmA |= ((unsigned)((balA >> REPLANE(p)) & 1ULL)) << p;
            while (rmA) {
                const int p = __builtin_ctz(rmA); rmA &= (rmA - 1u);
                const int gi = p * N_NODES + (int)((nodesA >> (8 * p)) & 0xffULL);
                const float* wr = W_in + (size_t)gi * DIM;
                float s = 0.f;
                #pragma unroll
                for (int q = 0; q < 4; ++q) {
                    const int off = (q & 1) * 4 + (q >> 1) * 512 + lane * 8;
                    const float4 fx = *(const float4*)(xrA + off);
                    const float4 fw = *(const float4*)(wr + off);
                    s = fmaf(fx.x, fw.x, s); s = fmaf(fx.y, fw.y, s);
                    s = fmaf(fx.z, fw.z, s); s = fmaf(fx.w, fw.w, s);
                }
                #pragma unroll
                for (int off = 32; off >= 1; off >>= 1)
                    s += __shfl_xor(s, off, 64);
                const float lf = s + b_in[gi];
                myA = (myp == p) ? lf : myA;
            }
            const unsigned long long balB = __ballot(fabsf(myB) < MARGIN);
            unsigned rmB = 0;
            #pragma unroll
            for (int p = 0; p < PAR; ++p)
                rmB |= ((unsigned)((balB >> REPLANE(p)) & 1ULL)) << p;
            while (rmB) {
                const int p = __builtin_ctz(rmB); rmB &= (rmB - 1u);
                const int gi = p * N_NODES + (int)((nodesB >> (8 * p)) & 0xffULL);
                const float* wr = W_in + (size_t)gi * DIM;
                float s = 0.f;
                #pragma unroll
                for (int q = 0; q < 4; ++q) {
                    const int off = (q & 1) * 4 + (q >> 1) * 512 + lane * 8;
                    const float4 fx = *(const float4*)(xrB + off);
                    const float4 fw = *(const float4*)(wr + off);
                    s = fmaf(fx.x, fw.x, s); s = fmaf(fx.y, fw.y, s);
                    s = fmaf(fx.z, fw.z, s); s = fmaf(fx.w, fw.w, s);
                }
                #pragma unroll
                for (int off = 32; off >= 1; off >>= 1)
                    s += __shfl_xor(s, off, 64);
                const float lf = s + b_in[gi];
                myB = (myp == p) ? lf : myB;
            }
        }

        // per-lane silu; decisions via one ballot per row
        const float actA = myA / (1.0f + __expf(-myA));
        const float actB = myB / (1.0f + __expf(-myB));
        const unsigned long long posA = __ballot(myA > 0.0f);
        const unsigned long long posB = __ballot(myB > 0.0f);

        // Phase C: dual-row axpy; gidx rematerialized from nodes, act
        // broadcast just-in-time -- keeps peak VGPR pressure low while the
        // A/B streams' loads cover each other's FMA chains.
        #pragma unroll
        for (int p = 0; p < PAR; ++p) {
            const int gAp = p * N_NODES + (int)((nodesA >> (8 * p)) & 0xffULL);
            const float aA = __shfl(actA, REPLANE(p), 64);
            const unsigned short* woA = WoT + (size_t)gAp * DIM;
            const uint4 u0 = *(const uint4*)(woA + lane * 8);
            const uint4 u1 = *(const uint4*)(woA + 512 + lane * 8);
            const int gBp = p * N_NODES + (int)((nodesB >> (8 * p)) & 0xffULL);
            const float aB = __shfl(actB, REPLANE(p), 64);
            const unsigned short* woB = WoT + (size_t)gBp * DIM;
            const uint4 v0 = *(const uint4*)(woB + lane * 8);
            const uint4 v1 = *(const uint4*)(woB + 512 + lane * 8);
            half2v h_;
            h_ = as_h2(u0.x); accA[0]  = fmaf((float)h_.x, aA, accA[0]);  accA[1]  = fmaf((float)h_.y, aA, accA[1]);
            h_ = as_h2(u0.y); accA[2]  = fmaf((float)h_.x, aA, accA[2]);  accA[3]  = fmaf((float)h_.y, aA, accA[3]);
            h_ = as_h2(u0.z); accA[4]  = fmaf((float)h_.x, aA, accA[4]);  accA[5]  = fmaf((float)h_.y, aA, accA[5]);
            h_ = as_h2(u0.w); accA[6]  = fmaf((float)h_.x, aA, accA[6]);  accA[7]  = fmaf((float)h_.y, aA, accA[7]);
            h_ = as_h2(u1.x); accA[8]  = fmaf((float)h_.x, aA, accA[8]);  accA[9]  = fmaf((float)h_.y, aA, accA[9]);
            h_ = as_h2(u1.y); accA[10] = fmaf((float)h_.x, aA, accA[10]); accA[11] = fmaf((float)h_.y, aA, accA[11]);
            h_ = as_h2(u1.z); accA[12] = fmaf((float)h_.x, aA, accA[12]); accA[13] = fmaf((float)h_.y, aA, accA[13]);
            h_ = as_h2(u1.w); accA[14] = fmaf((float)h_.x, aA, accA[14]); accA[15] = fmaf((float)h_.y, aA, accA[15]);
            h_ = as_h2(v0.x); accB[0]  = fmaf((float)h_.x, aB, accB[0]);  accB[1]  = fmaf((float)h_.y, aB, accB[1]);
            h_ = as_h2(v0.y); accB[2]  = fmaf((float)h_.x, aB, accB[2]);  accB[3]  = fmaf((float)h_.y, aB, accB[3]);
            h_ = as_h2(v0.z); accB[4]  = fmaf((float)h_.x, aB, accB[4]);  accB[5]  = fmaf((float)h_.y, aB, accB[5]);
            h_ = as_h2(v0.w); accB[6]  = fmaf((float)h_.x, aB, accB[6]);  accB[7]  = fmaf((float)h_.y, aB, accB[7]);
            h_ = as_h2(v1.x); accB[8]  = fmaf((float)h_.x, aB, accB[8]);  accB[9]  = fmaf((float)h_.y, aB, accB[9]);
            h_ = as_h2(v1.y); accB[10] = fmaf((float)h_.x, aB, accB[10]); accB[11] = fmaf((float)h_.y, aB, accB[11]);
            h_ = as_h2(v1.z); accB[12] = fmaf((float)h_.x, aB, accB[12]); accB[13] = fmaf((float)h_.y, aB, accB[13]);
            h_ = as_h2(v1.w); accB[14] = fmaf((float)h_.x, aB, accB[14]); accB[15] = fmaf((float)h_.y, aB, accB[15]);
        }

        if (d < DEPTH) {
            #pragma unroll
            for (int p = 0; p < PAR; ++p) {
                const int npA = (int)((nodesA >> (8 * p)) & 0xffULL);
                const unsigned long long nnA = (unsigned long long)
                    (2 * npA + 1 + (int)((posA >> REPLANE(p)) & 1ULL));
                nodesA = (nodesA & ~(0xffULL << (8 * p))) | (nnA << (8 * p));
                const int npB = (int)((nodesB >> (8 * p)) & 0xffULL);
                const unsigned long long nnB = (unsigned long long)
                    (2 * npB + 1 + (int)((posB >> REPLANE(p)) & 1ULL));
                nodesB = (nodesB & ~(0xffULL << (8 * p))) | (nnB << (8 * p));
            }
        }
    }

    float* orowA = out + (size_t)rowA * DIM;
    *(float4*)(orowA + lane * 8 + 0)       = make_float4(accA[0],  accA[1],  accA[2],  accA[3]);
    *(float4*)(orowA + lane * 8 + 4)       = make_float4(accA[4],  accA[5],  accA[6],  accA[7]);
    *(float4*)(orowA + 512 + lane * 8 + 0) = make_float4(accA[8],  accA[9],  accA[10], accA[11]);
    *(float4*)(orowA + 512 + lane * 8 + 4) = make_float4(accA[12], accA[13], accA[14], accA[15]);
    if (hasB) {
        float* orowB = out + (size_t)rowB * DIM;
        *(float4*)(orowB + lane * 8 + 0)       = make_float4(accB[0],  accB[1],  accB[2],  accB[3]);
        *(float4*)(orowB + lane * 8 + 4)       = make_float4(accB[4],  accB[5],  accB[6],  accB[7]);
        *(float4*)(orowB + 512 + lane * 8 + 0) = make_float4(accB[8],  accB[9],  accB[10], accB[11]);
        *(float4*)(orowB + 512 + lane * 8 + 4) = make_float4(accB[12], accB[13], accB[14], accB[15]);
    }
}

// ---------------------------------------------------------------------------
// Fallback (no workspace): fp32 gather both stages. Correct but slow.
// ---------------------------------------------------------------------------
__global__ __launch_bounds__(256) void fff_fallback_kernel(
    const float* __restrict__ x, const float* __restrict__ W_in,
    const float* __restrict__ b_in, const float* __restrict__ W_out,
    float* __restrict__ out, int B)
{
    const int wave = (int)((blockIdx.x * blockDim.x + threadIdx.x) >> 6);
    const int lane = (int)(threadIdx.x & 63);
    if (wave >= B) return;

    const float* xr = x + (size_t)wave * DIM;
    float4 x4[4];
    x4[0] = *(const float4*)(xr + lane * 8 + 0);
    x4[1] = *(const float4*)(xr + lane * 8 + 4);
    x4[2] = *(const float4*)(xr + 512 + lane * 8 + 0);
    x4[3] = *(const float4*)(xr + 512 + lane * 8 + 4);

    float acc[16];
    #pragma unroll
    for (int i = 0; i < 16; ++i) acc[i] = 0.f;
    int node[PAR];
    #pragma unroll
    for (int p = 0; p < PAR; ++p) node[p] = 0;

    for (int d = 0; d <= DEPTH; ++d) {
        #pragma unroll
        for (int p = 0; p < PAR; ++p) {
            const int gidx = p * N_NODES + node[p];
            const float* wr = W_in + (size_t)gidx * DIM;
            const float4 wa = *(const float4*)(wr + lane * 8 + 0);
            const float4 wb = *(const float4*)(wr + lane * 8 + 4);
            const float4 wc = *(const float4*)(wr + 512 + lane * 8 + 0);
            const float4 wd = *(const float4*)(wr + 512 + lane * 8 + 4);
            float s = 0.f;
            s = fmaf(x4[0].x, wa.x, s); s = fmaf(x4[0].y, wa.y, s);
            s = fmaf(x4[0].z, wa.z, s); s = fmaf(x4[0].w, wa.w, s);
            s = fmaf(x4[1].x, wb.x, s); s = fmaf(x4[1].y, wb.y, s);
            s = fmaf(x4[1].z, wb.z, s); s = fmaf(x4[1].w, wb.w, s);
            s = fmaf(x4[2].x, wc.x, s); s = fmaf(x4[2].y, wc.y, s);
            s = fmaf(x4[2].z, wc.z, s); s = fmaf(x4[2].w, wc.w, s);
            s = fmaf(x4[3].x, wd.x, s); s = fmaf(x4[3].y, wd.y, s);
            s = fmaf(x4[3].z, wd.z, s); s = fmaf(x4[3].w, wd.w, s);
            #pragma unroll
            for (int off = 32; off >= 1; off >>= 1)
                s += __shfl_xor(s, off, 64);
            const float logit = s + b_in[gidx];
            const float act = logit / (1.0f + __expf(-logit));
            #pragma unroll
            for (int k = 0; k < 2; ++k) {
                #pragma unroll
                for (int j = 0; j < 8; ++j) {
                    const int e = k * 512 + lane * 8 + j;
                    acc[k * 8 + j] = fmaf(act, W_out[(size_t)e * WIDTH + gidx], acc[k * 8 + j]);
                }
            }
            node[p] = 2 * node[p] + 1 + ((logit > 0.0f) ? 1 : 0);
        }
    }

    float* orow = out + (size_t)wave * DIM;
    *(float4*)(orow + lane * 8 + 0)       = make_float4(acc[0],  acc[1],  acc[2],  acc[3]);
    *(float4*)(orow + lane * 8 + 4)       = make_float4(acc[4],  acc[5],  acc[6],  acc[7]);
    *(float4*)(orow + 512 + lane * 8 + 0) = make_float4(acc[8],  acc[9],  acc[10], acc[11]);
    *(float4*)(orow + 512 + lane * 8 + 4) = make_float4(acc[12], acc[13], acc[14], acc[15]);
}

extern "C" void kernel_launch(void* const* d_in, const int* in_sizes, int n_in,
                              void* d_out, int out_size, void* d_ws, size_t ws_size,
                              hipStream_t stream) {
    const float* oldx  = (const float*)d_in[0];
    const float* W_in  = (const float*)d_in[1];
    const float* b_in  = (const float*)d_in[2];
    const float* W_out = (const float*)d_in[3];
    float* out = (float*)d_out;

    const int B = in_sizes[0] / DIM;   // 8192 rows

    const size_t half = (size_t)WIDTH * DIM * sizeof(unsigned short);  // 4.18 MB
    const bool use_lp = (d_ws != nullptr) && (ws_size >= 2 * half);

    if (use_lp) {
        unsigned short* WoT = (unsigned short*)d_ws;
        unsigned int*   Wh  = (unsigned int*)((char*)d_ws + half);
        prep_kernel<<<TRANS_BLOCKS + 1024, 256, 0, stream>>>(W_out, W_in, WoT, Wh);
        const int waves = (B + 1) / 2;            // two rows per wave
        const int blocks = (waves + 3) / 4;       // 4 waves per block
        fff_fused2_kernel<<<blocks, 256, 0, stream>>>(oldx, W_in, b_in, Wh, WoT, out, B);
    } else {
        const int blocks = (B + 3) / 4;
        fff_fallback_kernel<<<blocks, 256, 0, stream>>>(oldx, W_in, b_in, W_out, out, B);
    }
}